// Round 2
// baseline (1301.473 us; speedup 1.0000x reference)
//
#include <hip/hip_runtime.h>
#include <hip/hip_bf16.h>
#include <math.h>

// ---- model dims ----
#define HIDN 768
#define NHEAD 12
#define DHEAD 64
#define WWIN 256
#define NCHUNK 16
#define NLAYER 2
#define FFND 3072
#define NLABEL 8921
#define NB 2
#define NS 4096
#define NBS (NB*NS)

// fused projection output: [q | k | v | kg | vg] along N
#define QSTR 3840
#define OQ   0
#define OK_  768
#define OV   1536
#define OKG  2304
#define OVG  3072

typedef __attribute__((ext_vector_type(8))) short bf16x8;
typedef __attribute__((ext_vector_type(4))) float f32x4;

__device__ __forceinline__ float bf2f(unsigned short u){
  union { unsigned int i; float f; } v; v.i = ((unsigned int)u) << 16; return v.f;
}
__device__ __forceinline__ unsigned short f2bf(float f){
  __hip_bfloat16 h = __float2bfloat16(f);
  return *reinterpret_cast<unsigned short*>(&h);
}
__device__ __forceinline__ void unpack2(unsigned int u, float& a, float& b){
  union { unsigned int i; float f; } x, y;
  x.i = u << 16; y.i = u & 0xffff0000u; a = x.f; b = y.f;
}
// async global->LDS, 16B per lane; LDS dest = ldsbase + lane*16
__device__ __forceinline__ void gld_lds16(const unsigned short* g, unsigned short* l){
  __builtin_amdgcn_global_load_lds((const __attribute__((address_space(1))) unsigned int*)g,
                                   (__attribute__((address_space(3))) unsigned int*)l, 16, 0, 0);
}

// bijective XCD-chunked swizzle of a linear block id (m204 variant)
__device__ __forceinline__ int xcd_swz(int orig, int nwg){
  int q = nwg >> 3, r = nwg & 7;
  int x = orig & 7, lo = orig >> 3;
  return (x < r ? x*(q+1) : r*(q+1) + (x-r)*q) + lo;
}

// DPP row-rotate helper: rotate within 16-lane row by N, combine for reductions.
#define DPP_ROR_F(x, N) __builtin_bit_cast(float, __builtin_amdgcn_update_dpp( \
    0, __builtin_bit_cast(int, (x)), 0x120 + (N), 0xf, 0xf, true))
__device__ __forceinline__ float rowmax16(float x){
  x = fmaxf(x, DPP_ROR_F(x, 1));
  x = fmaxf(x, DPP_ROR_F(x, 2));
  x = fmaxf(x, DPP_ROR_F(x, 4));
  x = fmaxf(x, DPP_ROR_F(x, 8));
  return x;
}
__device__ __forceinline__ float rowsum16(float x){
  x = x + DPP_ROR_F(x, 1);
  x = x + DPP_ROR_F(x, 2);
  x = x + DPP_ROR_F(x, 4);
  x = x + DPP_ROR_F(x, 8);
  return x;
}

// ---------------- embedding (fp32 inputs) ----------------
__global__ __launch_bounds__(256) void embed_k(const int* __restrict__ ids,
    const float* __restrict__ we, const float* __restrict__ pe,
    float* __restrict__ y){
  int i = blockIdx.x*256 + threadIdx.x;
  int row = i / HIDN; int d = i - row*HIDN;
  int s = row & (NS-1);
  int id = ids[row];
  y[i] = we[(size_t)id*HIDN + d] + pe[(size_t)s*HIDN + d];
}

// ---------------- layernorm (optional residual), fp32 + bf16 outputs ----------------
__global__ __launch_bounds__(256) void ln_k(const float* A, const float* R,
    const float* __restrict__ sc, const float* __restrict__ bi,
    float* X, unsigned short* XB){
  __shared__ float red[256];
  int row = blockIdx.x, t = threadIdx.x;
  size_t base = (size_t)row*HIDN;
  float v0 = A[base+t], v1 = A[base+t+256], v2 = A[base+t+512];
  if (R){ v0 += R[base+t]; v1 += R[base+t+256]; v2 += R[base+t+512]; }
  red[t] = v0+v1+v2; __syncthreads();
  for (int st=128; st>0; st>>=1){ if (t<st) red[t]+=red[t+st]; __syncthreads(); }
  float mean = red[0] * (1.0f/HIDN); __syncthreads();
  float d0=v0-mean, d1=v1-mean, d2=v2-mean;
  red[t] = d0*d0+d1*d1+d2*d2; __syncthreads();
  for (int st=128; st>0; st>>=1){ if (t<st) red[t]+=red[t+st]; __syncthreads(); }
  float rs = rsqrtf(red[0] * (1.0f/HIDN) + 1e-5f);
  float o0 = d0*rs*sc[t]     + bi[t];
  float o1 = d1*rs*sc[t+256] + bi[t+256];
  float o2 = d2*rs*sc[t+512] + bi[t+512];
  X[base+t]=o0; X[base+t+256]=o1; X[base+t+512]=o2;
  XB[base+t]=f2bf(o0); XB[base+t+256]=f2bf(o1); XB[base+t+512]=f2bf(o2);
}

// ---------------- fp32 [R,C] -> bf16 transpose [C,R] ----------------
__global__ __launch_bounds__(256) void transpose_k(const float* __restrict__ src,
    unsigned short* __restrict__ dst, int R, int C){
  __shared__ unsigned short tile[32][33];
  int ct = blockIdx.x*32, rt = blockIdx.y*32;
  int tx = threadIdx.x, ty = threadIdx.y;     // 32 x 8
  #pragma unroll
  for (int i=0;i<4;i++) tile[ty+i*8][tx] = f2bf(src[(size_t)(rt+ty+i*8)*C + ct + tx]);
  __syncthreads();
  #pragma unroll
  for (int i=0;i<4;i++) dst[(size_t)(ct+ty+i*8)*R + rt + tx] = tile[tx][ty+i*8];
}

// ---------------- bias concat for fused qkv/kg/vg projection ----------------
__global__ __launch_bounds__(256) void pack_bias_k(const float* __restrict__ bq,
    const float* __restrict__ bk, const float* __restrict__ bv,
    const float* __restrict__ bkg, const float* __restrict__ bvg,
    float* __restrict__ out){
  int i = blockIdx.x*256 + threadIdx.x;      // 0 .. NLAYER*3840-1
  int l = i / QSTR; int j = i - l*QSTR;
  int seg = j / HIDN, d = j - seg*HIDN;
  const float* src = (seg==0)?bq : (seg==1)?bk : (seg==2)?bv : (seg==3)?bkg : bvg;
  out[i] = src[l*HIDN + d];
}

// ---------------- GEMM 128x128xBK64, global_load_lds staging, XOR-swizzled LDS ----
// C[M,N] = A[M,K](bf16) * BT[N,K]^T (bf16) + bias(fp32). M%128==0, N%128==0, K%64==0.
template<int OUTF32, int GELU>
__global__ __launch_bounds__(256) void gemm128(const unsigned short* __restrict__ A,
    const unsigned short* __restrict__ BT, const float* __restrict__ bias,
    void* __restrict__ Cp, int M, int N, int K){
  __shared__ unsigned short As[128*64];
  __shared__ unsigned short Bs[128*64];
  const int tid = threadIdx.x;
  const int nwg = gridDim.x * gridDim.y;
  const int wg = xcd_swz(blockIdx.y * gridDim.x + blockIdx.x, nwg);
  const int m0 = (wg / gridDim.x) * 128, n0 = (wg % gridDim.x) * 128;
  const int lane = tid & 63, w = tid >> 6;
  const int n = lane & 15, quad = lane >> 4;
  const int wm = (w>>1)*64, wn = (w&1)*64;
  const int lr = lane >> 3, site = lane & 7;   // staging: 8 rows x 8 sites per instr
  f32x4 acc[4][4] = {};
  for (int kb=0; kb<K; kb+=64){
    #pragma unroll
    for (int j=0;j<4;j++){
      int rbase = w*32 + j*8;
      int r = rbase + lr;
      int q = site ^ (r & 7);
      gld_lds16(A  + (size_t)(m0+r)*K + kb + q*8, &As[rbase*64]);
      gld_lds16(BT + (size_t)(n0+r)*K + kb + q*8, &Bs[rbase*64]);
    }
    __syncthreads();
    #pragma unroll
    for (int ks=0; ks<2; ks++){
      bf16x8 a[4], b[4];
      #pragma unroll
      for (int i=0;i<4;i++){
        int rm = wm + i*16 + n;
        a[i] = *(const bf16x8*)&As[rm*64 + (((ks*4+quad) ^ (rm&7))<<3)];
        int rn = wn + i*16 + n;
        b[i] = *(const bf16x8*)&Bs[rn*64 + (((ks*4+quad) ^ (rn&7))<<3)];
      }
      #pragma unroll
      for (int mi=0;mi<4;mi++)
      #pragma unroll
      for (int ni=0;ni<4;ni++)
        acc[mi][ni] = __builtin_amdgcn_mfma_f32_16x16x32_bf16(a[mi], b[ni], acc[mi][ni], 0,0,0);
    }
    __syncthreads();
  }
  #pragma unroll
  for (int mi=0; mi<4; mi++)
  #pragma unroll
  for (int ni=0; ni<4; ni++){
    int col = n0 + wn + ni*16 + n;
    float bsv = bias[col];
    #pragma unroll
    for (int rg=0; rg<4; rg++){
      int row = m0 + wm + mi*16 + quad*4 + rg;
      float v = acc[mi][ni][rg] + bsv;
      if (GELU) v = 0.5f*v*(1.0f + erff(v*0.70710678118f));
      if (OUTF32) ((float*)Cp)[(size_t)row*N + col] = v;
      else ((unsigned short*)Cp)[(size_t)row*N + col] = f2bf(v);
    }
  }
}

// ---------------- GEMM 256x256xBK64, double-buffered LDS, 1-tile-ahead prefetch ----
// Same data contract as gemm128. 512 threads = 8 waves (2M x 4N), per-wave out 128x64.
// LDS 128 KiB: 2 buffers x (A 256x64 + B 256x64) bf16, 8-row XOR swizzle (T2).
// Prefetch of tile kt+1 is issued BEFORE compute of tile kt; the single
// __syncthreads() per tile drains vmcnt for loads issued a full tile earlier.
template<int OUTF32, int GELU>
__global__ __launch_bounds__(512) void gemm256(const unsigned short* __restrict__ A,
    const unsigned short* __restrict__ BT, const float* __restrict__ bias,
    void* __restrict__ Cp, int M, int N, int K){
  __shared__ unsigned short AsB[2][256*64];
  __shared__ unsigned short BsB[2][256*64];
  const int tid = threadIdx.x;
  const int gx = gridDim.x;
  const int nwg = gx * gridDim.y;
  const int wg = xcd_swz(blockIdx.y*gx + blockIdx.x, nwg);
  const int m0 = (wg / gx) * 256, n0 = (wg % gx) * 256;
  const int lane = tid & 63, w = tid >> 6;
  const int n = lane & 15, quad = lane >> 4;
  const int wm = (w>>2)*128, wn = (w&3)*64;
  const int lr = lane >> 3, site = lane & 7;
  const int NK = K >> 6;
  f32x4 acc[8][4] = {};

  auto stage = [&](int b, int kb){
    #pragma unroll
    for (int j=0;j<4;j++){
      int rbase = w*32 + j*8;
      int r = rbase + lr;
      int q = site ^ (r & 7);
      gld_lds16(A  + (size_t)(m0+r)*K + kb + q*8, &AsB[b][rbase*64]);
      gld_lds16(BT + (size_t)(n0+r)*K + kb + q*8, &BsB[b][rbase*64]);
    }
  };

  stage(0, 0);
  __syncthreads();                      // vmcnt(0) drain -> tile 0 resident
  for (int kt=0; kt<NK; ++kt){
    const int b = kt & 1;
    if (kt+1 < NK) stage(b^1, (kt+1)<<6);   // full-tile-ahead prefetch into other buffer
    const unsigned short* As_ = AsB[b];
    const unsigned short* Bs_ = BsB[b];
    bf16x8 bfr[2][4];
    #pragma unroll
    for (int ks=0;ks<2;ks++)
    #pragma unroll
    for (int ni=0;ni<4;ni++){
      int rn = wn + ni*16 + n;
      bfr[ks][ni] = *(const bf16x8*)&Bs_[rn*64 + (((ks*4+quad) ^ (rn&7))<<3)];
    }
    #pragma unroll
    for (int mi=0;mi<8;mi++){
      int rm = wm + mi*16 + n;
      bf16x8 a0 = *(const bf16x8*)&As_[rm*64 + (((quad)     ^ (rm&7))<<3)];
      bf16x8 a1 = *(const bf16x8*)&As_[rm*64 + (((4+quad)   ^ (rm&7))<<3)];
      #pragma unroll
      for (int ni=0;ni<4;ni++)
        acc[mi][ni] = __builtin_amdgcn_mfma_f32_16x16x32_bf16(a0, bfr[0][ni], acc[mi][ni],0,0,0);
      #pragma unroll
      for (int ni=0;ni<4;ni++)
        acc[mi][ni] = __builtin_amdgcn_mfma_f32_16x16x32_bf16(a1, bfr[1][ni], acc[mi][ni],0,0,0);
    }
    if (kt+1 < NK) __syncthreads();     // one barrier/tile; drains next tile's loads (old)
  }
  #pragma unroll
  for (int mi=0;mi<8;mi++)
  #pragma unroll
  for (int ni=0;ni<4;ni++){
    int col = n0 + wn + ni*16 + n;
    float bsv = bias[col];
    #pragma unroll
    for (int rg=0;rg<4;rg++){
      int row = m0 + wm + mi*16 + quad*4 + rg;
      float v = acc[mi][ni][rg] + bsv;
      if (GELU) v = 0.5f*v*(1.0f + erff(v*0.70710678118f));
      if (OUTF32) ((float*)Cp)[(size_t)row*N + col] = v;
      else ((unsigned short*)Cp)[(size_t)row*N + col] = f2bf(v);
    }
  }
}

// ---------------- MFMA banded sliding-window attention (+ global key column) ----------------
// qkv: fused [NBS, 3840] bf16 with columns [q|k|v|kg|vg]
__global__ __launch_bounds__(256, 2) void band_attn_mfma(
    const unsigned short* __restrict__ qkv, const int* __restrict__ am,
    unsigned short* __restrict__ Out){
  __shared__ unsigned short Kt[64*72];        // [key][dim], pad 72
  __shared__ unsigned short Vt[64*72];        // [dim][key], pad 72 (transposed)
  __shared__ unsigned short Pbuf[4*64*72];    // per-wave P tile [q][key], pad 72
  __shared__ float mk[64];                    // per-key additive mask (0 / -1e9)
  __shared__ unsigned short kgs[64];
  __shared__ unsigned short vgs[64];

  const int tid = threadIdx.x;
  const int bid = xcd_swz(blockIdx.x, gridDim.x);
  const int c = bid & (NCHUNK-1);
  const int h = (bid / NCHUNK) % NHEAD;
  const int b = bid / (NCHUNK*NHEAD);
  const int lane = tid & 63, w = tid >> 6;
  const int n = lane & 15, quad = lane >> 4;
  const int qbase = w * 64;
  unsigned short* Pw = Pbuf + w*64*72;

  if (tid < 8)       ((uint4*)kgs)[tid]   = ((const uint4*)(qkv + ((size_t)b*NS)*QSTR + OKG + h*DHEAD))[tid];
  else if (tid < 16) ((uint4*)vgs)[tid-8] = ((const uint4*)(qkv + ((size_t)b*NS)*QSTR + OVG + h*DHEAD))[tid-8];
  __syncthreads();

  bf16x8 aQ[4][2];
  #pragma unroll
  for (int mi=0; mi<4; mi++)
  #pragma unroll
  for (int ks=0; ks<2; ks++)
    aQ[mi][ks] = *(const bf16x8*)(qkv + ((size_t)(b*NS + c*WWIN + qbase + 16*mi + n))*QSTR
                                    + OQ + h*DHEAD + ks*32 + quad*8);

  f32x4 sacc[4] = {};
  #pragma unroll
  for (int ks=0; ks<2; ks++){
    bf16x8 bg = *(const bf16x8*)(kgs + ks*32 + quad*8);
    bf16x8 z8 = {};
    bg = (n == 0) ? bg : z8;
    #pragma unroll
    for (int mi=0; mi<4; mi++)
      sacc[mi] = __builtin_amdgcn_mfma_f32_16x16x32_bf16(aQ[mi][ks], bg, sacc[mi], 0,0,0);
  }
  float mst[4][4], lpt[4][4];
  f32x4 apv[4][4];
  float vgf[4];
  #pragma unroll
  for (int ni=0; ni<4; ni++) vgf[ni] = bf2f(vgs[16*ni + n]);
  #pragma unroll
  for (int mi=0; mi<4; mi++)
  #pragma unroll
  for (int rg=0; rg<4; rg++){
    float sg = __shfl(sacc[mi][rg], lane & 48);
    mst[mi][rg] = sg * 0.125f;
    lpt[mi][rg] = (n == 0) ? 1.0f : 0.0f;
  }
  #pragma unroll
  for (int mi=0; mi<4; mi++)
  #pragma unroll
  for (int ni=0; ni<4; ni++)
  #pragma unroll
  for (int rg=0; rg<4; rg++) apv[mi][ni][rg] = vgf[ni];

  for (int t=0; t<12; t++){
    __syncthreads();
    {
      int i = tid >> 2, d0 = (tid & 3) * 8;
      int kp = (c-1)*WWIN + t*64 + i;
      int kpc = min(max(kp, 0), NS-1);
      size_t gb = ((size_t)(b*NS + kpc))*QSTR + h*DHEAD;
      uint4 k0 = *(const uint4*)(qkv + gb + OK_ + d0);
      uint4 k1 = *(const uint4*)(qkv + gb + OK_ + d0 + 32);
      uint4 v0 = *(const uint4*)(qkv + gb + OV + d0);
      uint4 v1 = *(const uint4*)(qkv + gb + OV + d0 + 32);
      *(uint4*)(Kt + i*72 + d0) = k0;
      *(uint4*)(Kt + i*72 + d0 + 32) = k1;
      const unsigned short* s0 = (const unsigned short*)&v0;
      const unsigned short* s1 = (const unsigned short*)&v1;
      #pragma unroll
      for (int j=0;j<8;j++){
        Vt[(d0+j)*72 + i] = s0[j];
        Vt[(d0+32+j)*72 + i] = s1[j];
      }
      if ((tid & 3) == 0)
        mk[i] = (kp >= 1 && kp < NS && am[b*NS + kpc] > 0) ? 0.0f : -1e9f;
    }
    __syncthreads();

    float mkv[4];
    #pragma unroll
    for (int ni=0; ni<4; ni++) mkv[ni] = mk[16*ni + n];

    f32x4 accs[4][4] = {};
    #pragma unroll
    for (int ks=0; ks<2; ks++){
      bf16x8 bK[4];
      #pragma unroll
      for (int ni=0; ni<4; ni++)
        bK[ni] = *(const bf16x8*)(Kt + (16*ni + n)*72 + ks*32 + quad*8);
      #pragma unroll
      for (int mi=0; mi<4; mi++)
      #pragma unroll
      for (int ni=0; ni<4; ni++)
        accs[mi][ni] = __builtin_amdgcn_mfma_f32_16x16x32_bf16(aQ[mi][ks], bK[ni], accs[mi][ni], 0,0,0);
    }

    #pragma unroll
    for (int mi=0; mi<4; mi++){
      float sv[4][4];
      #pragma unroll
      for (int ni=0; ni<4; ni++)
      #pragma unroll
      for (int rg=0; rg<4; rg++){
        int kk = t*64 + 16*ni + n;
        int pr = qbase + 16*mi + quad*4 + rg;
        float s = accs[mi][ni][rg]*0.125f + mkv[ni];
        if ((unsigned)(kk - pr) > 512u) s = -1e9f;
        sv[ni][rg] = s;
      }
      #pragma unroll
      for (int rg=0; rg<4; rg++){
        float rm = fmaxf(fmaxf(sv[0][rg], sv[1][rg]), fmaxf(sv[2][rg], sv[3][rg]));
        rm = rowmax16(rm);
        float mold = mst[mi][rg];
        float mnew = fmaxf(mold, rm);
        float alpha = __expf(mold - mnew);
        mst[mi][rg] = mnew;
        float psum = 0.f;
        #pragma unroll
        for (int ni=0; ni<4; ni++){
          float pv = __expf(sv[ni][rg] - mnew);
          sv[ni][rg] = pv;
          psum += pv;
        }
        lpt[mi][rg] = lpt[mi][rg]*alpha + psum;
        #pragma unroll
        for (int ni=0; ni<4; ni++) apv[mi][ni][rg] *= alpha;
        int prow = 16*mi + quad*4 + rg;
        #pragma unroll
        for (int ni=0; ni<4; ni++)
          Pw[prow*72 + 16*ni + n] = f2bf(sv[ni][rg]);
      }
    }

    #pragma unroll
    for (int ks2=0; ks2<2; ks2++){
      bf16x8 aP[4], bV[4];
      #pragma unroll
      for (int mi=0; mi<4; mi++)
        aP[mi] = *(const bf16x8*)(Pw + (16*mi + n)*72 + ks2*32 + quad*8);
      #pragma unroll
      for (int ni=0; ni<4; ni++)
        bV[ni] = *(const bf16x8*)(Vt + (16*ni + n)*72 + ks2*32 + quad*8);
      #pragma unroll
      for (int mi=0; mi<4; mi++)
      #pragma unroll
      for (int ni=0; ni<4; ni++)
        apv[mi][ni] = __builtin_amdgcn_mfma_f32_16x16x32_bf16(aP[mi], bV[ni], apv[mi][ni], 0,0,0);
    }
  }

  #pragma unroll
  for (int mi=0; mi<4; mi++)
  #pragma unroll
  for (int rg=0; rg<4; rg++){
    float L = rowsum16(lpt[mi][rg]);
    float inv = 1.0f / L;
    int q = c*WWIN + qbase + 16*mi + quad*4 + rg;
    size_t ob = ((size_t)(b*NS + q))*HIDN + h*DHEAD;
    #pragma unroll
    for (int ni=0; ni<4; ni++)
      Out[ob + 16*ni + n] = f2bf(apv[mi][ni][rg] * inv);
  }
}

// ---------------- split-flash global (CLS) attention: partials over 128-key chunks ----
__global__ __launch_bounds__(128) void gattn_part(
    const unsigned short* __restrict__ QG0, const unsigned short* __restrict__ qkv,
    const int* __restrict__ am, float* __restrict__ part){
  __shared__ float qs[64];
  __shared__ float ps[128];
  __shared__ float red[128];
  int t = threadIdx.x;
  int cx = blockIdx.x, h = blockIdx.y, b = blockIdx.z;
  if (t < 32){
    float a, bb; unpack2(((const unsigned int*)(QG0 + (size_t)b*128*HIDN + h*DHEAD))[t], a, bb);
    qs[2*t]=a*0.125f; qs[2*t+1]=bb*0.125f;
  }
  __syncthreads();
  int kp = cx*128 + t;
  const unsigned int* kr = (const unsigned int*)(qkv + ((size_t)(b*NS+kp))*QSTR + OKG + h*DHEAD);
  float sv = 0.f;
  #pragma unroll
  for (int j=0;j<32;j++){ float a,bb; unpack2(kr[j],a,bb); sv += qs[2*j]*a + qs[2*j+1]*bb; }
  if (am[b*NS+kp] <= 0) sv = -1e9f;
  red[t] = sv; __syncthreads();
  for (int st=64; st>0; st>>=1){ if (t<st) red[t] = fmaxf(red[t], red[t+st]); __syncthreads(); }
  float M = red[0]; __syncthreads();
  float e = __expf(sv - M);
  ps[t] = e; red[t] = e; __syncthreads();
  for (int st=64; st>0; st>>=1){ if (t<st) red[t] += red[t+st]; __syncthreads(); }
  float L = red[0];
  float* po = part + ((size_t)((b*NHEAD+h)*32 + cx))*66;
  if (t==0){ po[0]=M; po[1]=L; }
  if (t < 64){
    float o = 0.f;
    #pragma unroll 4
    for (int i=0;i<128;i++)
      o += ps[i] * bf2f(qkv[((size_t)(b*NS + cx*128 + i))*QSTR + OVG + h*DHEAD + t]);
    po[2+t] = o;
  }
}

__global__ __launch_bounds__(64) void gattn_reduce(const float* __restrict__ part,
    unsigned short* __restrict__ Out){
  int bh = blockIdx.x;
  int b = bh / NHEAD, h = bh % NHEAD;
  int d = threadIdx.x;
  const float* pp = part + (size_t)bh*32*66;
  float M = -1e30f;
  for (int c2=0;c2<32;c2++) M = fmaxf(M, pp[c2*66]);
  float L = 0.f, o = 0.f;
  for (int c2=0;c2<32;c2++){
    float w = __expf(pp[c2*66] - M);
    L += pp[c2*66+1]*w;
    o += pp[c2*66+2+d]*w;
  }
  Out[((size_t)b*NS)*HIDN + h*DHEAD + d] = f2bf(o / L);
}

// ---------------- classification head on CLS token (all fp32), 4-way d-split ----
__global__ __launch_bounds__(256) void head_k(const float* __restrict__ X,
    const float* __restrict__ HW, const float* __restrict__ HB,
    float* __restrict__ Outp){
  __shared__ float red[256];
  __shared__ float xs[HIDN];
  int b = blockIdx.y;
  int base = blockIdx.x*64;
  int t = threadIdx.x;
  const float* x0 = X + (size_t)b*NS*HIDN;
  for (int i=t; i<HIDN; i+=256) xs[i] = x0[i];
  __syncthreads();
  int n = base + (t & 63);
  int dp = t >> 6;             // 0..3, 192 dims each
  float a = 0.f;
  if (n < NLABEL){
    #pragma unroll 4
    for (int d=dp*192; d<dp*192+192; ++d)
      a += xs[d] * HW[(size_t)d*NLABEL + n];
  }
  red[t] = a; __syncthreads();
  if (t < 64 && n < NLABEL)
    Outp[(size_t)b*NLABEL + n] = red[t]+red[t+64]+red[t+128]+red[t+192] + HB[n];
}

extern "C" void kernel_launch(void* const* d_in, const int* in_sizes, int n_in,
                              void* d_out, int out_size, void* d_ws, size_t ws_size,
                              hipStream_t stream){
  (void)in_sizes; (void)n_in; (void)out_size; (void)ws_size;
  const int* ids = (const int*)d_in[0];
  const int* am  = (const int*)d_in[1];
  const float* we  = (const float*)d_in[2];
  const float* pe  = (const float*)d_in[3];
  const float* elns= (const float*)d_in[4];
  const float* elnb= (const float*)d_in[5];
  const float* Wq  = (const float*)d_in[6];
  const float* bq  = (const float*)d_in[7];
  const float* Wk  = (const float*)d_in[8];
  const float* bk  = (const float*)d_in[9];
  const float* Wv  = (const float*)d_in[10];
  const float* bv  = (const float*)d_in[11];
  const float* Wqg = (const float*)d_in[12];
  const float* bqg = (const float*)d_in[13];
  const float* Wkg = (const float*)d_in[14];
  const float* bkg = (const float*)d_in[15];
  const float* Wvg = (const float*)d_in[16];
  const float* bvg = (const float*)d_in[17];
  const float* Wo  = (const float*)d_in[18];
  const float* bo  = (const float*)d_in[19];
  const float* l1s = (const float*)d_in[20];
  const float* l1b = (const float*)d_in[21];
  const float* W1  = (const float*)d_in[22];
  const float* b1  = (const float*)d_in[23];
  const float* W2  = (const float*)d_in[24];
  const float* b2  = (const float*)d_in[25];
  const float* l2s = (const float*)d_in[26];
  const float* l2b = (const float*)d_in[27];
  const float* hW  = (const float*)d_in[28];
  const float* hB  = (const float*)d_in[29];

  char* ws = (char*)d_ws;
  float* x = (float*)ws;                                    // 25,165,824 B
  float* y = (float*)(ws + 25165824);                       // 25,165,824 B
  unsigned short* xb   = (unsigned short*)(ws + 50331648);  // 12,582,912 B
  unsigned short* qkvb = (unsigned short*)(ws + 62914560);  // 8192*3840*2 = 62,914,560 B
  unsigned short* qg0b = (unsigned short*)(ws + 125829120); // 393,216 B
  float* part = (float*)(ws + 126222336);                   // 202,752 B
  unsigned short* ao   = (unsigned short*)(ws + 126425088); // 12,582,912 B
  unsigned short* hbuf = (unsigned short*)(ws + 139008000); // 50,331,648 B
  unsigned short* wt   = (unsigned short*)(ws + 189339648); // 35,389,440 B
  float* bpack = (float*)(ws + 224729088);                  // 2*3840*4 = 30,720 B

  const size_t SQ = 589824;        // 768*768
  const size_t SW = 2359296;       // 768*3072
  const size_t PERL = 7*SQ + 2*SW;

  auto tr = [&](const float* src, unsigned short* dst, int R, int C){
    dim3 g(C/32, R/32), blk(32, 8);
    transpose_k<<<g, blk, 0, stream>>>(src, dst, R, C);
  };
  // layout per layer: [q | k | v | kg | vg] (fused N=3840), then qg, o, W1, W2
  for (int l=0; l<NLAYER; l++){
    unsigned short* base = wt + (size_t)l*PERL;
    tr(Wq  + (size_t)l*SQ, base + 0*SQ, 768, 768);
    tr(Wk  + (size_t)l*SQ, base + 1*SQ, 768, 768);
    tr(Wv  + (size_t)l*SQ, base + 2*SQ, 768, 768);
    tr(Wkg + (size_t)l*SQ, base + 3*SQ, 768, 768);
    tr(Wvg + (size_t)l*SQ, base + 4*SQ, 768, 768);
    tr(Wqg + (size_t)l*SQ, base + 5*SQ, 768, 768);
    tr(Wo  + (size_t)l*SQ, base + 6*SQ, 768, 768);
    tr(W1  + (size_t)l*SW, base + 7*SQ, 768, 3072);
    tr(W2  + (size_t)l*SW, base + 7*SQ + SW, 3072, 768);
  }
  pack_bias_k<<<(NLAYER*QSTR)/256, 256, 0, stream>>>(bq, bk, bv, bkg, bvg, bpack);

  embed_k<<<(NBS*HIDN)/256, 256, 0, stream>>>(ids, we, pe, y);
  ln_k<<<NBS, 256, 0, stream>>>(y, nullptr, elns, elnb, x, xb);

  for (int l=0; l<NLAYER; l++){
    unsigned short* base = wt + (size_t)l*PERL;
    // fused q/k/v/kg/vg projection: N = 5*768 = 3840 at 256^2 tiles: 15x32 = 480 blocks
    gemm256<0,0><<<dim3(15,32), 512, 0, stream>>>(xb, base, bpack + (size_t)l*QSTR,
                                                  qkvb, NBS, QSTR, 768);
    // qg needed only for CLS row: project first 128 rows of each batch
    for (int b=0; b<NB; b++)
      gemm128<0,0><<<dim3(6,1), 256, 0, stream>>>(xb + (size_t)b*NS*HIDN, base + 5*SQ,
                                                  bqg + l*768, qg0b + (size_t)b*128*HIDN,
                                                  128, 768, 768);
    band_attn_mfma<<<NB*NHEAD*NCHUNK, 256, 0, stream>>>(qkvb, am, ao);
    gattn_part<<<dim3(32, NHEAD, NB), 128, 0, stream>>>(qg0b, qkvb, am, part);
    gattn_reduce<<<NB*NHEAD, 64, 0, stream>>>(part, ao);
    gemm128<1,0><<<dim3(6,64), 256, 0, stream>>>(ao, base + 6*SQ, bo + l*768, y, NBS, 768, 768);
    ln_k<<<NBS, 256, 0, stream>>>(y, x, l1s + l*768, l1b + l*768, x, xb);
    // FFN1 at 256^2: 12x32 = 384 blocks
    gemm256<0,1><<<dim3(12,32), 512, 0, stream>>>(xb, base + 7*SQ, b1 + l*3072, hbuf, NBS, 3072, 768);
    gemm128<1,0><<<dim3(6,64), 256, 0, stream>>>(hbuf, base + 7*SQ + SW, b2 + l*768, y, NBS, 768, 3072);
    ln_k<<<NBS, 256, 0, stream>>>(y, x, l2s + l*768, l2b + l*768, x, xb);
  }

  head_k<<<dim3((NLABEL+63)/64, NB), 256, 0, stream>>>(x, hW, hB, (float*)d_out);
}

// Round 3
// 1174.702 us; speedup vs baseline: 1.1079x; 1.1079x over previous
//
#include <hip/hip_runtime.h>
#include <hip/hip_bf16.h>
#include <math.h>

// ---- model dims ----
#define HIDN 768
#define NHEAD 12
#define DHEAD 64
#define WWIN 256
#define NCHUNK 16
#define NLAYER 2
#define FFND 3072
#define NLABEL 8921
#define NB 2
#define NS 4096
#define NBS (NB*NS)

// fused projection output: [q | k | v | kg | vg] along N
#define QSTR 3840
#define OQ   0
#define OK_  768
#define OV   1536
#define OKG  2304
#define OVG  3072

typedef __attribute__((ext_vector_type(8))) short bf16x8;
typedef __attribute__((ext_vector_type(4))) float f32x4;

__device__ __forceinline__ float bf2f(unsigned short u){
  union { unsigned int i; float f; } v; v.i = ((unsigned int)u) << 16; return v.f;
}
__device__ __forceinline__ unsigned short f2bf(float f){
  __hip_bfloat16 h = __float2bfloat16(f);
  return *reinterpret_cast<unsigned short*>(&h);
}
__device__ __forceinline__ void unpack2(unsigned int u, float& a, float& b){
  union { unsigned int i; float f; } x, y;
  x.i = u << 16; y.i = u & 0xffff0000u; a = x.f; b = y.f;
}
// async global->LDS, 16B per lane; LDS dest = ldsbase + lane*16
__device__ __forceinline__ void gld_lds16(const unsigned short* g, unsigned short* l){
  __builtin_amdgcn_global_load_lds((const __attribute__((address_space(1))) unsigned int*)g,
                                   (__attribute__((address_space(3))) unsigned int*)l, 16, 0, 0);
}

// bijective XCD-chunked swizzle of a linear block id (m204 variant)
__device__ __forceinline__ int xcd_swz(int orig, int nwg){
  int q = nwg >> 3, r = nwg & 7;
  int x = orig & 7, lo = orig >> 3;
  return (x < r ? x*(q+1) : r*(q+1) + (x-r)*q) + lo;
}

// DPP row-rotate helper: rotate within 16-lane row by N, combine for reductions.
#define DPP_ROR_F(x, N) __builtin_bit_cast(float, __builtin_amdgcn_update_dpp( \
    0, __builtin_bit_cast(int, (x)), 0x120 + (N), 0xf, 0xf, true))
__device__ __forceinline__ float rowmax16(float x){
  x = fmaxf(x, DPP_ROR_F(x, 1));
  x = fmaxf(x, DPP_ROR_F(x, 2));
  x = fmaxf(x, DPP_ROR_F(x, 4));
  x = fmaxf(x, DPP_ROR_F(x, 8));
  return x;
}
__device__ __forceinline__ float rowsum16(float x){
  x = x + DPP_ROR_F(x, 1);
  x = x + DPP_ROR_F(x, 2);
  x = x + DPP_ROR_F(x, 4);
  x = x + DPP_ROR_F(x, 8);
  return x;
}

// ---------------- embedding (fp32 inputs) ----------------
__global__ __launch_bounds__(256) void embed_k(const int* __restrict__ ids,
    const float* __restrict__ we, const float* __restrict__ pe,
    float* __restrict__ y){
  int i = blockIdx.x*256 + threadIdx.x;
  int row = i / HIDN; int d = i - row*HIDN;
  int s = row & (NS-1);
  int id = ids[row];
  y[i] = we[(size_t)id*HIDN + d] + pe[(size_t)s*HIDN + d];
}

// ---------------- layernorm (optional residual), fp32 + bf16 outputs ----------------
__global__ __launch_bounds__(256) void ln_k(const float* A, const float* R,
    const float* __restrict__ sc, const float* __restrict__ bi,
    float* X, unsigned short* XB){
  __shared__ float red[256];
  int row = blockIdx.x, t = threadIdx.x;
  size_t base = (size_t)row*HIDN;
  float v0 = A[base+t], v1 = A[base+t+256], v2 = A[base+t+512];
  if (R){ v0 += R[base+t]; v1 += R[base+t+256]; v2 += R[base+t+512]; }
  red[t] = v0+v1+v2; __syncthreads();
  for (int st=128; st>0; st>>=1){ if (t<st) red[t]+=red[t+st]; __syncthreads(); }
  float mean = red[0] * (1.0f/HIDN); __syncthreads();
  float d0=v0-mean, d1=v1-mean, d2=v2-mean;
  red[t] = d0*d0+d1*d1+d2*d2; __syncthreads();
  for (int st=128; st>0; st>>=1){ if (t<st) red[t]+=red[t+st]; __syncthreads(); }
  float rs = rsqrtf(red[0] * (1.0f/HIDN) + 1e-5f);
  float o0 = d0*rs*sc[t]     + bi[t];
  float o1 = d1*rs*sc[t+256] + bi[t+256];
  float o2 = d2*rs*sc[t+512] + bi[t+512];
  X[base+t]=o0; X[base+t+256]=o1; X[base+t+512]=o2;
  XB[base+t]=f2bf(o0); XB[base+t+256]=f2bf(o1); XB[base+t+512]=f2bf(o2);
}

// ---------------- fp32 [R,C] -> bf16 transpose [C,R] ----------------
__global__ __launch_bounds__(256) void transpose_k(const float* __restrict__ src,
    unsigned short* __restrict__ dst, int R, int C){
  __shared__ unsigned short tile[32][33];
  int ct = blockIdx.x*32, rt = blockIdx.y*32;
  int tx = threadIdx.x, ty = threadIdx.y;     // 32 x 8
  #pragma unroll
  for (int i=0;i<4;i++) tile[ty+i*8][tx] = f2bf(src[(size_t)(rt+ty+i*8)*C + ct + tx]);
  __syncthreads();
  #pragma unroll
  for (int i=0;i<4;i++) dst[(size_t)(ct+ty+i*8)*R + rt + tx] = tile[tx][ty+i*8];
}

// ---------------- bias concat for fused qkv/kg/vg projection ----------------
__global__ __launch_bounds__(256) void pack_bias_k(const float* __restrict__ bq,
    const float* __restrict__ bk, const float* __restrict__ bv,
    const float* __restrict__ bkg, const float* __restrict__ bvg,
    float* __restrict__ out){
  int i = blockIdx.x*256 + threadIdx.x;      // 0 .. NLAYER*3840-1
  int l = i / QSTR; int j = i - l*QSTR;
  int seg = j / HIDN, d = j - seg*HIDN;
  const float* src = (seg==0)?bq : (seg==1)?bk : (seg==2)?bv : (seg==3)?bkg : bvg;
  out[i] = src[l*HIDN + d];
}

// ---------------- GEMM 128x128xBK64, global_load_lds staging, XOR-swizzled LDS ----
// C[M,N] = A[M,K](bf16) * BT[N,K]^T (bf16) + bias(fp32). M%128==0, N%128==0, K%64==0.
template<int OUTF32, int GELU>
__global__ __launch_bounds__(256) void gemm128(const unsigned short* __restrict__ A,
    const unsigned short* __restrict__ BT, const float* __restrict__ bias,
    void* __restrict__ Cp, int M, int N, int K){
  __shared__ unsigned short As[128*64];
  __shared__ unsigned short Bs[128*64];
  const int tid = threadIdx.x;
  const int nwg = gridDim.x * gridDim.y;
  const int wg = xcd_swz(blockIdx.y * gridDim.x + blockIdx.x, nwg);
  const int m0 = (wg / gridDim.x) * 128, n0 = (wg % gridDim.x) * 128;
  const int lane = tid & 63, w = tid >> 6;
  const int n = lane & 15, quad = lane >> 4;
  const int wm = (w>>1)*64, wn = (w&1)*64;
  const int lr = lane >> 3, site = lane & 7;   // staging: 8 rows x 8 sites per instr
  f32x4 acc[4][4] = {};
  for (int kb=0; kb<K; kb+=64){
    #pragma unroll
    for (int j=0;j<4;j++){
      int rbase = w*32 + j*8;
      int r = rbase + lr;
      int q = site ^ (r & 7);
      gld_lds16(A  + (size_t)(m0+r)*K + kb + q*8, &As[rbase*64]);
      gld_lds16(BT + (size_t)(n0+r)*K + kb + q*8, &Bs[rbase*64]);
    }
    __syncthreads();
    #pragma unroll
    for (int ks=0; ks<2; ks++){
      bf16x8 a[4], b[4];
      #pragma unroll
      for (int i=0;i<4;i++){
        int rm = wm + i*16 + n;
        a[i] = *(const bf16x8*)&As[rm*64 + (((ks*4+quad) ^ (rm&7))<<3)];
        int rn = wn + i*16 + n;
        b[i] = *(const bf16x8*)&Bs[rn*64 + (((ks*4+quad) ^ (rn&7))<<3)];
      }
      #pragma unroll
      for (int mi=0;mi<4;mi++)
      #pragma unroll
      for (int ni=0;ni<4;ni++)
        acc[mi][ni] = __builtin_amdgcn_mfma_f32_16x16x32_bf16(a[mi], b[ni], acc[mi][ni], 0,0,0);
    }
    __syncthreads();
  }
  #pragma unroll
  for (int mi=0; mi<4; mi++)
  #pragma unroll
  for (int ni=0; ni<4; ni++){
    int col = n0 + wn + ni*16 + n;
    float bsv = bias[col];
    #pragma unroll
    for (int rg=0; rg<4; rg++){
      int row = m0 + wm + mi*16 + quad*4 + rg;
      float v = acc[mi][ni][rg] + bsv;
      if (GELU) v = 0.5f*v*(1.0f + erff(v*0.70710678118f));
      if (OUTF32) ((float*)Cp)[(size_t)row*N + col] = v;
      else ((unsigned short*)Cp)[(size_t)row*N + col] = f2bf(v);
    }
  }
}

// ---------------- GEMM 256x256xBK64, double-buffered LDS, counted-vmcnt pipeline ----
// T4: raw s_barrier + s_waitcnt vmcnt(8) keeps the next tile's 8 global_load_lds
// in flight across the barrier (never drains to 0 in the main loop).
// Each stage() = 8 gld_lds per wave; vmcnt(8) completes exactly the oldest 8
// (the buffer about to be consumed). Second barrier protects the buffer from
// being re-staged while other waves still ds_read it.
template<int OUTF32, int GELU>
__global__ __launch_bounds__(512) void gemm256(const unsigned short* __restrict__ A,
    const unsigned short* __restrict__ BT, const float* __restrict__ bias,
    void* __restrict__ Cp, int M, int N, int K){
  __shared__ unsigned short AsB[2][256*64];
  __shared__ unsigned short BsB[2][256*64];
  const int tid = threadIdx.x;
  const int gx = gridDim.x;
  const int nwg = gx * gridDim.y;
  const int wg = xcd_swz(blockIdx.y*gx + blockIdx.x, nwg);
  const int m0 = (wg / gx) * 256, n0 = (wg % gx) * 256;
  const int lane = tid & 63, w = tid >> 6;
  const int n = lane & 15, quad = lane >> 4;
  const int wm = (w>>2)*128, wn = (w&3)*64;
  const int lr = lane >> 3, site = lane & 7;
  const int NK = K >> 6;
  f32x4 acc[8][4] = {};

  auto stage = [&](int b, int kb){
    #pragma unroll
    for (int j=0;j<4;j++){
      int rbase = w*32 + j*8;
      int r = rbase + lr;
      int q = site ^ (r & 7);
      gld_lds16(A  + (size_t)(m0+r)*K + kb + q*8, &AsB[b][rbase*64]);
      gld_lds16(BT + (size_t)(n0+r)*K + kb + q*8, &BsB[b][rbase*64]);
    }
  };

  stage(0, 0);                                 // 8 loads in flight
  for (int kt=0; kt<NK; ++kt){
    const int b = kt & 1;
    if (kt+1 < NK){
      stage(b^1, (kt+1)<<6);                   // +8 -> 16 in flight
      asm volatile("s_waitcnt vmcnt(8)" ::: "memory");   // oldest 8 (buf b) done
    } else {
      asm volatile("s_waitcnt vmcnt(0)" ::: "memory");
    }
    __builtin_amdgcn_s_barrier();              // all waves' buf-b loads landed
    const unsigned short* As_ = AsB[b];
    const unsigned short* Bs_ = BsB[b];
    bf16x8 bfr[2][4];
    #pragma unroll
    for (int ks=0;ks<2;ks++)
    #pragma unroll
    for (int ni=0;ni<4;ni++){
      int rn = wn + ni*16 + n;
      bfr[ks][ni] = *(const bf16x8*)&Bs_[rn*64 + (((ks*4+quad) ^ (rn&7))<<3)];
    }
    #pragma unroll
    for (int mi=0;mi<8;mi++){
      int rm = wm + mi*16 + n;
      bf16x8 a0 = *(const bf16x8*)&As_[rm*64 + (((quad)     ^ (rm&7))<<3)];
      bf16x8 a1 = *(const bf16x8*)&As_[rm*64 + (((4+quad)   ^ (rm&7))<<3)];
      #pragma unroll
      for (int ni=0;ni<4;ni++)
        acc[mi][ni] = __builtin_amdgcn_mfma_f32_16x16x32_bf16(a0, bfr[0][ni], acc[mi][ni],0,0,0);
      #pragma unroll
      for (int ni=0;ni<4;ni++)
        acc[mi][ni] = __builtin_amdgcn_mfma_f32_16x16x32_bf16(a1, bfr[1][ni], acc[mi][ni],0,0,0);
    }
    if (kt+1 < NK) __builtin_amdgcn_s_barrier();  // buf b fully consumed before re-stage
  }
  #pragma unroll
  for (int mi=0;mi<8;mi++)
  #pragma unroll
  for (int ni=0;ni<4;ni++){
    int col = n0 + wn + ni*16 + n;
    float bsv = bias[col];
    #pragma unroll
    for (int rg=0;rg<4;rg++){
      int row = m0 + wm + mi*16 + quad*4 + rg;
      float v = acc[mi][ni][rg] + bsv;
      if (GELU) v = 0.5f*v*(1.0f + erff(v*0.70710678118f));
      if (OUTF32) ((float*)Cp)[(size_t)row*N + col] = v;
      else ((unsigned short*)Cp)[(size_t)row*N + col] = f2bf(v);
    }
  }
}

// ---------------- MFMA banded sliding-window attention (+ global key column) ----------------
// qkv: fused [NBS, 3840] bf16 with columns [q|k|v|kg|vg]
__global__ __launch_bounds__(256, 2) void band_attn_mfma(
    const unsigned short* __restrict__ qkv, const int* __restrict__ am,
    unsigned short* __restrict__ Out){
  __shared__ unsigned short Kt[64*72];        // [key][dim], pad 72
  __shared__ unsigned short Vt[64*72];        // [dim][key], pad 72 (transposed)
  __shared__ unsigned short Pbuf[4*64*72];    // per-wave P tile [q][key], pad 72
  __shared__ float mk[64];                    // per-key additive mask (0 / -1e9)
  __shared__ unsigned short kgs[64];
  __shared__ unsigned short vgs[64];

  const int tid = threadIdx.x;
  const int bid = xcd_swz(blockIdx.x, gridDim.x);
  const int c = bid & (NCHUNK-1);
  const int h = (bid / NCHUNK) % NHEAD;
  const int b = bid / (NCHUNK*NHEAD);
  const int lane = tid & 63, w = tid >> 6;
  const int n = lane & 15, quad = lane >> 4;
  const int qbase = w * 64;
  unsigned short* Pw = Pbuf + w*64*72;

  if (tid < 8)       ((uint4*)kgs)[tid]   = ((const uint4*)(qkv + ((size_t)b*NS)*QSTR + OKG + h*DHEAD))[tid];
  else if (tid < 16) ((uint4*)vgs)[tid-8] = ((const uint4*)(qkv + ((size_t)b*NS)*QSTR + OVG + h*DHEAD))[tid-8];
  __syncthreads();

  bf16x8 aQ[4][2];
  #pragma unroll
  for (int mi=0; mi<4; mi++)
  #pragma unroll
  for (int ks=0; ks<2; ks++)
    aQ[mi][ks] = *(const bf16x8*)(qkv + ((size_t)(b*NS + c*WWIN + qbase + 16*mi + n))*QSTR
                                    + OQ + h*DHEAD + ks*32 + quad*8);

  f32x4 sacc[4] = {};
  #pragma unroll
  for (int ks=0; ks<2; ks++){
    bf16x8 bg = *(const bf16x8*)(kgs + ks*32 + quad*8);
    bf16x8 z8 = {};
    bg = (n == 0) ? bg : z8;
    #pragma unroll
    for (int mi=0; mi<4; mi++)
      sacc[mi] = __builtin_amdgcn_mfma_f32_16x16x32_bf16(aQ[mi][ks], bg, sacc[mi], 0,0,0);
  }
  float mst[4][4], lpt[4][4];
  f32x4 apv[4][4];
  float vgf[4];
  #pragma unroll
  for (int ni=0; ni<4; ni++) vgf[ni] = bf2f(vgs[16*ni + n]);
  #pragma unroll
  for (int mi=0; mi<4; mi++)
  #pragma unroll
  for (int rg=0; rg<4; rg++){
    float sg = __shfl(sacc[mi][rg], lane & 48);
    mst[mi][rg] = sg * 0.125f;
    lpt[mi][rg] = (n == 0) ? 1.0f : 0.0f;
  }
  #pragma unroll
  for (int mi=0; mi<4; mi++)
  #pragma unroll
  for (int ni=0; ni<4; ni++)
  #pragma unroll
  for (int rg=0; rg<4; rg++) apv[mi][ni][rg] = vgf[ni];

  for (int t=0; t<12; t++){
    __syncthreads();
    {
      int i = tid >> 2, d0 = (tid & 3) * 8;
      int kp = (c-1)*WWIN + t*64 + i;
      int kpc = min(max(kp, 0), NS-1);
      size_t gb = ((size_t)(b*NS + kpc))*QSTR + h*DHEAD;
      uint4 k0 = *(const uint4*)(qkv + gb + OK_ + d0);
      uint4 k1 = *(const uint4*)(qkv + gb + OK_ + d0 + 32);
      uint4 v0 = *(const uint4*)(qkv + gb + OV + d0);
      uint4 v1 = *(const uint4*)(qkv + gb + OV + d0 + 32);
      *(uint4*)(Kt + i*72 + d0) = k0;
      *(uint4*)(Kt + i*72 + d0 + 32) = k1;
      const unsigned short* s0 = (const unsigned short*)&v0;
      const unsigned short* s1 = (const unsigned short*)&v1;
      #pragma unroll
      for (int j=0;j<8;j++){
        Vt[(d0+j)*72 + i] = s0[j];
        Vt[(d0+32+j)*72 + i] = s1[j];
      }
      if ((tid & 3) == 0)
        mk[i] = (kp >= 1 && kp < NS && am[b*NS + kpc] > 0) ? 0.0f : -1e9f;
    }
    __syncthreads();

    float mkv[4];
    #pragma unroll
    for (int ni=0; ni<4; ni++) mkv[ni] = mk[16*ni + n];

    f32x4 accs[4][4] = {};
    #pragma unroll
    for (int ks=0; ks<2; ks++){
      bf16x8 bK[4];
      #pragma unroll
      for (int ni=0; ni<4; ni++)
        bK[ni] = *(const bf16x8*)(Kt + (16*ni + n)*72 + ks*32 + quad*8);
      #pragma unroll
      for (int mi=0; mi<4; mi++)
      #pragma unroll
      for (int ni=0; ni<4; ni++)
        accs[mi][ni] = __builtin_amdgcn_mfma_f32_16x16x32_bf16(aQ[mi][ks], bK[ni], accs[mi][ni], 0,0,0);
    }

    #pragma unroll
    for (int mi=0; mi<4; mi++){
      float sv[4][4];
      #pragma unroll
      for (int ni=0; ni<4; ni++)
      #pragma unroll
      for (int rg=0; rg<4; rg++){
        int kk = t*64 + 16*ni + n;
        int pr = qbase + 16*mi + quad*4 + rg;
        float s = accs[mi][ni][rg]*0.125f + mkv[ni];
        if ((unsigned)(kk - pr) > 512u) s = -1e9f;
        sv[ni][rg] = s;
      }
      #pragma unroll
      for (int rg=0; rg<4; rg++){
        float rm = fmaxf(fmaxf(sv[0][rg], sv[1][rg]), fmaxf(sv[2][rg], sv[3][rg]));
        rm = rowmax16(rm);
        float mold = mst[mi][rg];
        float mnew = fmaxf(mold, rm);
        float alpha = __expf(mold - mnew);
        mst[mi][rg] = mnew;
        float psum = 0.f;
        #pragma unroll
        for (int ni=0; ni<4; ni++){
          float pv = __expf(sv[ni][rg] - mnew);
          sv[ni][rg] = pv;
          psum += pv;
        }
        lpt[mi][rg] = lpt[mi][rg]*alpha + psum;
        #pragma unroll
        for (int ni=0; ni<4; ni++) apv[mi][ni][rg] *= alpha;
        int prow = 16*mi + quad*4 + rg;
        #pragma unroll
        for (int ni=0; ni<4; ni++)
          Pw[prow*72 + 16*ni + n] = f2bf(sv[ni][rg]);
      }
    }

    #pragma unroll
    for (int ks2=0; ks2<2; ks2++){
      bf16x8 aP[4], bV[4];
      #pragma unroll
      for (int mi=0; mi<4; mi++)
        aP[mi] = *(const bf16x8*)(Pw + (16*mi + n)*72 + ks2*32 + quad*8);
      #pragma unroll
      for (int ni=0; ni<4; ni++)
        bV[ni] = *(const bf16x8*)(Vt + (16*ni + n)*72 + ks2*32 + quad*8);
      #pragma unroll
      for (int mi=0; mi<4; mi++)
      #pragma unroll
      for (int ni=0; ni<4; ni++)
        apv[mi][ni] = __builtin_amdgcn_mfma_f32_16x16x32_bf16(aP[mi], bV[ni], apv[mi][ni], 0,0,0);
    }
  }

  #pragma unroll
  for (int mi=0; mi<4; mi++)
  #pragma unroll
  for (int rg=0; rg<4; rg++){
    float L = rowsum16(lpt[mi][rg]);
    float inv = 1.0f / L;
    int q = c*WWIN + qbase + 16*mi + quad*4 + rg;
    size_t ob = ((size_t)(b*NS + q))*HIDN + h*DHEAD;
    #pragma unroll
    for (int ni=0; ni<4; ni++)
      Out[ob + 16*ni + n] = f2bf(apv[mi][ni][rg] * inv);
  }
}

// ---------------- split-flash global (CLS) attention: partials over 128-key chunks ----
__global__ __launch_bounds__(128) void gattn_part(
    const unsigned short* __restrict__ QG0, const unsigned short* __restrict__ qkv,
    const int* __restrict__ am, float* __restrict__ part){
  __shared__ float qs[64];
  __shared__ float ps[128];
  __shared__ float red[128];
  int t = threadIdx.x;
  int cx = blockIdx.x, h = blockIdx.y, b = blockIdx.z;
  if (t < 32){
    float a, bb; unpack2(((const unsigned int*)(QG0 + (size_t)b*128*HIDN + h*DHEAD))[t], a, bb);
    qs[2*t]=a*0.125f; qs[2*t+1]=bb*0.125f;
  }
  __syncthreads();
  int kp = cx*128 + t;
  const unsigned int* kr = (const unsigned int*)(qkv + ((size_t)(b*NS+kp))*QSTR + OKG + h*DHEAD);
  float sv = 0.f;
  #pragma unroll
  for (int j=0;j<32;j++){ float a,bb; unpack2(kr[j],a,bb); sv += qs[2*j]*a + qs[2*j+1]*bb; }
  if (am[b*NS+kp] <= 0) sv = -1e9f;
  red[t] = sv; __syncthreads();
  for (int st=64; st>0; st>>=1){ if (t<st) red[t] = fmaxf(red[t], red[t+st]); __syncthreads(); }
  float M = red[0]; __syncthreads();
  float e = __expf(sv - M);
  ps[t] = e; red[t] = e; __syncthreads();
  for (int st=64; st>0; st>>=1){ if (t<st) red[t] += red[t+st]; __syncthreads(); }
  float L = red[0];
  float* po = part + ((size_t)((b*NHEAD+h)*32 + cx))*66;
  if (t==0){ po[0]=M; po[1]=L; }
  if (t < 64){
    float o = 0.f;
    #pragma unroll 4
    for (int i=0;i<128;i++)
      o += ps[i] * bf2f(qkv[((size_t)(b*NS + cx*128 + i))*QSTR + OVG + h*DHEAD + t]);
    po[2+t] = o;
  }
}

__global__ __launch_bounds__(64) void gattn_reduce(const float* __restrict__ part,
    unsigned short* __restrict__ Out){
  int bh = blockIdx.x;
  int b = bh / NHEAD, h = bh % NHEAD;
  int d = threadIdx.x;
  const float* pp = part + (size_t)bh*32*66;
  float M = -1e30f;
  for (int c2=0;c2<32;c2++) M = fmaxf(M, pp[c2*66]);
  float L = 0.f, o = 0.f;
  for (int c2=0;c2<32;c2++){
    float w = __expf(pp[c2*66] - M);
    L += pp[c2*66+1]*w;
    o += pp[c2*66+2+d]*w;
  }
  Out[((size_t)b*NS)*HIDN + h*DHEAD + d] = f2bf(o / L);
}

// ---------------- classification head on CLS token (all fp32), 4-way d-split ----
__global__ __launch_bounds__(256) void head_k(const float* __restrict__ X,
    const float* __restrict__ HW, const float* __restrict__ HB,
    float* __restrict__ Outp){
  __shared__ float red[256];
  __shared__ float xs[HIDN];
  int b = blockIdx.y;
  int base = blockIdx.x*64;
  int t = threadIdx.x;
  const float* x0 = X + (size_t)b*NS*HIDN;
  for (int i=t; i<HIDN; i+=256) xs[i] = x0[i];
  __syncthreads();
  int n = base + (t & 63);
  int dp = t >> 6;             // 0..3, 192 dims each
  float a = 0.f;
  if (n < NLABEL){
    #pragma unroll 4
    for (int d=dp*192; d<dp*192+192; ++d)
      a += xs[d] * HW[(size_t)d*NLABEL + n];
  }
  red[t] = a; __syncthreads();
  if (t < 64 && n < NLABEL)
    Outp[(size_t)b*NLABEL + n] = red[t]+red[t+64]+red[t+128]+red[t+192] + HB[n];
}

extern "C" void kernel_launch(void* const* d_in, const int* in_sizes, int n_in,
                              void* d_out, int out_size, void* d_ws, size_t ws_size,
                              hipStream_t stream){
  (void)in_sizes; (void)n_in; (void)out_size; (void)ws_size;
  const int* ids = (const int*)d_in[0];
  const int* am  = (const int*)d_in[1];
  const float* we  = (const float*)d_in[2];
  const float* pe  = (const float*)d_in[3];
  const float* elns= (const float*)d_in[4];
  const float* elnb= (const float*)d_in[5];
  const float* Wq  = (const float*)d_in[6];
  const float* bq  = (const float*)d_in[7];
  const float* Wk  = (const float*)d_in[8];
  const float* bk  = (const float*)d_in[9];
  const float* Wv  = (const float*)d_in[10];
  const float* bv  = (const float*)d_in[11];
  const float* Wqg = (const float*)d_in[12];
  const float* bqg = (const float*)d_in[13];
  const float* Wkg = (const float*)d_in[14];
  const float* bkg = (const float*)d_in[15];
  const float* Wvg = (const float*)d_in[16];
  const float* bvg = (const float*)d_in[17];
  const float* Wo  = (const float*)d_in[18];
  const float* bo  = (const float*)d_in[19];
  const float* l1s = (const float*)d_in[20];
  const float* l1b = (const float*)d_in[21];
  const float* W1  = (const float*)d_in[22];
  const float* b1  = (const float*)d_in[23];
  const float* W2  = (const float*)d_in[24];
  const float* b2  = (const float*)d_in[25];
  const float* l2s = (const float*)d_in[26];
  const float* l2b = (const float*)d_in[27];
  const float* hW  = (const float*)d_in[28];
  const float* hB  = (const float*)d_in[29];

  char* ws = (char*)d_ws;
  float* x = (float*)ws;                                    // 25,165,824 B
  float* y = (float*)(ws + 25165824);                       // 25,165,824 B
  unsigned short* xb   = (unsigned short*)(ws + 50331648);  // 12,582,912 B
  unsigned short* qkvb = (unsigned short*)(ws + 62914560);  // 8192*3840*2 = 62,914,560 B
  unsigned short* qg0b = (unsigned short*)(ws + 125829120); // 393,216 B
  float* part = (float*)(ws + 126222336);                   // 202,752 B
  unsigned short* ao   = (unsigned short*)(ws + 126425088); // 12,582,912 B
  unsigned short* hbuf = (unsigned short*)(ws + 139008000); // 50,331,648 B
  unsigned short* wt   = (unsigned short*)(ws + 189339648); // 35,389,440 B
  float* bpack = (float*)(ws + 224729088);                  // 2*3840*4 = 30,720 B

  const size_t SQ = 589824;        // 768*768
  const size_t SW = 2359296;       // 768*3072
  const size_t PERL = 7*SQ + 2*SW;

  auto tr = [&](const float* src, unsigned short* dst, int R, int C){
    dim3 g(C/32, R/32), blk(32, 8);
    transpose_k<<<g, blk, 0, stream>>>(src, dst, R, C);
  };
  // layout per layer: [q | k | v | kg | vg] (fused N=3840), then qg, o, W1, W2
  for (int l=0; l<NLAYER; l++){
    unsigned short* base = wt + (size_t)l*PERL;
    tr(Wq  + (size_t)l*SQ, base + 0*SQ, 768, 768);
    tr(Wk  + (size_t)l*SQ, base + 1*SQ, 768, 768);
    tr(Wv  + (size_t)l*SQ, base + 2*SQ, 768, 768);
    tr(Wkg + (size_t)l*SQ, base + 3*SQ, 768, 768);
    tr(Wvg + (size_t)l*SQ, base + 4*SQ, 768, 768);
    tr(Wqg + (size_t)l*SQ, base + 5*SQ, 768, 768);
    tr(Wo  + (size_t)l*SQ, base + 6*SQ, 768, 768);
    tr(W1  + (size_t)l*SW, base + 7*SQ, 768, 3072);
    tr(W2  + (size_t)l*SW, base + 7*SQ + SW, 3072, 768);
  }
  pack_bias_k<<<(NLAYER*QSTR)/256, 256, 0, stream>>>(bq, bk, bv, bkg, bvg, bpack);

  embed_k<<<(NBS*HIDN)/256, 256, 0, stream>>>(ids, we, pe, y);
  ln_k<<<NBS, 256, 0, stream>>>(y, nullptr, elns, elnb, x, xb);

  for (int l=0; l<NLAYER; l++){
    unsigned short* base = wt + (size_t)l*PERL;
    // fused q/k/v/kg/vg projection: N = 5*768 = 3840 at 256^2 tiles: 15x32 = 480 blocks
    gemm256<0,0><<<dim3(15,32), 512, 0, stream>>>(xb, base, bpack + (size_t)l*QSTR,
                                                  qkvb, NBS, QSTR, 768);
    // qg needed only for CLS row: project first 128 rows of each batch
    for (int b=0; b<NB; b++)
      gemm128<0,0><<<dim3(6,1), 256, 0, stream>>>(xb + (size_t)b*NS*HIDN, base + 5*SQ,
                                                  bqg + l*768, qg0b + (size_t)b*128*HIDN,
                                                  128, 768, 768);
    band_attn_mfma<<<NB*NHEAD*NCHUNK, 256, 0, stream>>>(qkvb, am, ao);
    gattn_part<<<dim3(32, NHEAD, NB), 128, 0, stream>>>(qg0b, qkvb, am, part);
    gattn_reduce<<<NB*NHEAD, 64, 0, stream>>>(part, ao);
    gemm128<1,0><<<dim3(6,64), 256, 0, stream>>>(ao, base + 6*SQ, bo + l*768, y, NBS, 768, 768);
    ln_k<<<NBS, 256, 0, stream>>>(y, x, l1s + l*768, l1b + l*768, x, xb);
    // FFN1 at 256^2: 12x32 = 384 blocks
    gemm256<0,1><<<dim3(12,32), 512, 0, stream>>>(xb, base + 7*SQ, b1 + l*3072, hbuf, NBS, 3072, 768);
    gemm128<1,0><<<dim3(6,64), 256, 0, stream>>>(hbuf, base + 7*SQ + SW, b2 + l*768, y, NBS, 768, 3072);
    ln_k<<<NBS, 256, 0, stream>>>(y, x, l2s + l*768, l2b + l*768, x, xb);
  }

  head_k<<<dim3((NLABEL+63)/64, NB), 256, 0, stream>>>(x, hW, hB, (float*)d_out);
}

// Round 4
// 1164.543 us; speedup vs baseline: 1.1176x; 1.0087x over previous
//
#include <hip/hip_runtime.h>
#include <hip/hip_bf16.h>
#include <math.h>

// ---- model dims ----
#define HIDN 768
#define NHEAD 12
#define DHEAD 64
#define WWIN 256
#define NCHUNK 16
#define NLAYER 2
#define FFND 3072
#define NLABEL 8921
#define NB 2
#define NS 4096
#define NBS (NB*NS)

// fused projection output: [q | k | v | kg | vg] along N
#define QSTR 3840
#define OQ   0
#define OK_  768
#define OV   1536
#define OKG  2304
#define OVG  3072

typedef __attribute__((ext_vector_type(8))) short bf16x8;
typedef __attribute__((ext_vector_type(4))) float f32x4;

__device__ __forceinline__ float bf2f(unsigned short u){
  union { unsigned int i; float f; } v; v.i = ((unsigned int)u) << 16; return v.f;
}
__device__ __forceinline__ unsigned short f2bf(float f){
  __hip_bfloat16 h = __float2bfloat16(f);
  return *reinterpret_cast<unsigned short*>(&h);
}
__device__ __forceinline__ void unpack2(unsigned int u, float& a, float& b){
  union { unsigned int i; float f; } x, y;
  x.i = u << 16; y.i = u & 0xffff0000u; a = x.f; b = y.f;
}
// exact-GELU via A&S 7.1.26 erf approximation (|err| < 1.5e-7), no libcall
__device__ __forceinline__ float gelu_f(float v){
  float x = v * 0.70710678118f;
  float ax = fabsf(x);
  float t = 1.0f / (1.0f + 0.3275911f*ax);
  float poly = ((((1.061405429f*t - 1.453152027f)*t + 1.421413741f)*t
                - 0.284496736f)*t + 0.254829592f)*t;
  float y = 1.0f - poly*__expf(-x*x);
  float er = copysignf(y, x);
  return 0.5f*v*(1.0f + er);
}
// async global->LDS, 16B per lane; LDS dest = ldsbase + lane*16
__device__ __forceinline__ void gld_lds16(const unsigned short* g, unsigned short* l){
  __builtin_amdgcn_global_load_lds((const __attribute__((address_space(1))) unsigned int*)g,
                                   (__attribute__((address_space(3))) unsigned int*)l, 16, 0, 0);
}

// bijective XCD-chunked swizzle of a linear block id (m204 variant)
__device__ __forceinline__ int xcd_swz(int orig, int nwg){
  int q = nwg >> 3, r = nwg & 7;
  int x = orig & 7, lo = orig >> 3;
  return (x < r ? x*(q+1) : r*(q+1) + (x-r)*q) + lo;
}

// DPP row-rotate helper: rotate within 16-lane row by N, combine for reductions.
#define DPP_ROR_F(x, N) __builtin_bit_cast(float, __builtin_amdgcn_update_dpp( \
    0, __builtin_bit_cast(int, (x)), 0x120 + (N), 0xf, 0xf, true))
__device__ __forceinline__ float rowmax16(float x){
  x = fmaxf(x, DPP_ROR_F(x, 1));
  x = fmaxf(x, DPP_ROR_F(x, 2));
  x = fmaxf(x, DPP_ROR_F(x, 4));
  x = fmaxf(x, DPP_ROR_F(x, 8));
  return x;
}
__device__ __forceinline__ float rowsum16(float x){
  x = x + DPP_ROR_F(x, 1);
  x = x + DPP_ROR_F(x, 2);
  x = x + DPP_ROR_F(x, 4);
  x = x + DPP_ROR_F(x, 8);
  return x;
}

// ---------------- embedding (fp32 inputs) ----------------
__global__ __launch_bounds__(256) void embed_k(const int* __restrict__ ids,
    const float* __restrict__ we, const float* __restrict__ pe,
    float* __restrict__ y){
  int i = blockIdx.x*256 + threadIdx.x;
  int row = i / HIDN; int d = i - row*HIDN;
  int s = row & (NS-1);
  int id = ids[row];
  y[i] = we[(size_t)id*HIDN + d] + pe[(size_t)s*HIDN + d];
}

// ---------------- layernorm (optional residual), fp32 + bf16 outputs ----------------
__global__ __launch_bounds__(256) void ln_k(const float* A, const float* R,
    const float* __restrict__ sc, const float* __restrict__ bi,
    float* X, unsigned short* XB){
  __shared__ float red[256];
  int row = blockIdx.x, t = threadIdx.x;
  size_t base = (size_t)row*HIDN;
  float v0 = A[base+t], v1 = A[base+t+256], v2 = A[base+t+512];
  if (R){ v0 += R[base+t]; v1 += R[base+t+256]; v2 += R[base+t+512]; }
  red[t] = v0+v1+v2; __syncthreads();
  for (int st=128; st>0; st>>=1){ if (t<st) red[t]+=red[t+st]; __syncthreads(); }
  float mean = red[0] * (1.0f/HIDN); __syncthreads();
  float d0=v0-mean, d1=v1-mean, d2=v2-mean;
  red[t] = d0*d0+d1*d1+d2*d2; __syncthreads();
  for (int st=128; st>0; st>>=1){ if (t<st) red[t]+=red[t+st]; __syncthreads(); }
  float rs = rsqrtf(red[0] * (1.0f/HIDN) + 1e-5f);
  float o0 = d0*rs*sc[t]     + bi[t];
  float o1 = d1*rs*sc[t+256] + bi[t+256];
  float o2 = d2*rs*sc[t+512] + bi[t+512];
  X[base+t]=o0; X[base+t+256]=o1; X[base+t+512]=o2;
  XB[base+t]=f2bf(o0); XB[base+t+256]=f2bf(o1); XB[base+t+512]=f2bf(o2);
}

// ---------------- fp32 [R,C] -> bf16 transpose [C,R] ----------------
__global__ __launch_bounds__(256) void transpose_k(const float* __restrict__ src,
    unsigned short* __restrict__ dst, int R, int C){
  __shared__ unsigned short tile[32][33];
  int ct = blockIdx.x*32, rt = blockIdx.y*32;
  int tx = threadIdx.x, ty = threadIdx.y;     // 32 x 8
  #pragma unroll
  for (int i=0;i<4;i++) tile[ty+i*8][tx] = f2bf(src[(size_t)(rt+ty+i*8)*C + ct + tx]);
  __syncthreads();
  #pragma unroll
  for (int i=0;i<4;i++) dst[(size_t)(ct+ty+i*8)*R + rt + tx] = tile[tx][ty+i*8];
}

// ---------------- bias concat for fused qkv/kg/vg projection ----------------
__global__ __launch_bounds__(256) void pack_bias_k(const float* __restrict__ bq,
    const float* __restrict__ bk, const float* __restrict__ bv,
    const float* __restrict__ bkg, const float* __restrict__ bvg,
    float* __restrict__ out){
  int i = blockIdx.x*256 + threadIdx.x;      // 0 .. NLAYER*3840-1
  int l = i / QSTR; int j = i - l*QSTR;
  int seg = j / HIDN, d = j - seg*HIDN;
  const float* src = (seg==0)?bq : (seg==1)?bk : (seg==2)?bv : (seg==3)?bkg : bvg;
  out[i] = src[l*HIDN + d];
}

// ---------------- GEMM 128x128xBK64, global_load_lds staging, XOR-swizzled LDS ----
// C[M,N] = A[M,K](bf16) * BT[N,K]^T (bf16) + bias(fp32). M%128==0, N%128==0, K%64==0.
template<int OUTF32, int GELU>
__global__ __launch_bounds__(256) void gemm128(const unsigned short* __restrict__ A,
    const unsigned short* __restrict__ BT, const float* __restrict__ bias,
    void* __restrict__ Cp, int M, int N, int K){
  __shared__ unsigned short As[128*64];
  __shared__ unsigned short Bs[128*64];
  const int tid = threadIdx.x;
  const int nwg = gridDim.x * gridDim.y;
  const int wg = xcd_swz(blockIdx.y * gridDim.x + blockIdx.x, nwg);
  const int m0 = (wg / gridDim.x) * 128, n0 = (wg % gridDim.x) * 128;
  const int lane = tid & 63, w = tid >> 6;
  const int n = lane & 15, quad = lane >> 4;
  const int wm = (w>>1)*64, wn = (w&1)*64;
  const int lr = lane >> 3, site = lane & 7;   // staging: 8 rows x 8 sites per instr
  f32x4 acc[4][4] = {};
  for (int kb=0; kb<K; kb+=64){
    #pragma unroll
    for (int j=0;j<4;j++){
      int rbase = w*32 + j*8;
      int r = rbase + lr;
      int q = site ^ (r & 7);
      gld_lds16(A  + (size_t)(m0+r)*K + kb + q*8, &As[rbase*64]);
      gld_lds16(BT + (size_t)(n0+r)*K + kb + q*8, &Bs[rbase*64]);
    }
    __syncthreads();
    #pragma unroll
    for (int ks=0; ks<2; ks++){
      bf16x8 a[4], b[4];
      #pragma unroll
      for (int i=0;i<4;i++){
        int rm = wm + i*16 + n;
        a[i] = *(const bf16x8*)&As[rm*64 + (((ks*4+quad) ^ (rm&7))<<3)];
        int rn = wn + i*16 + n;
        b[i] = *(const bf16x8*)&Bs[rn*64 + (((ks*4+quad) ^ (rn&7))<<3)];
      }
      #pragma unroll
      for (int mi=0;mi<4;mi++)
      #pragma unroll
      for (int ni=0;ni<4;ni++)
        acc[mi][ni] = __builtin_amdgcn_mfma_f32_16x16x32_bf16(a[mi], b[ni], acc[mi][ni], 0,0,0);
    }
    __syncthreads();
  }
  #pragma unroll
  for (int mi=0; mi<4; mi++)
  #pragma unroll
  for (int ni=0; ni<4; ni++){
    int col = n0 + wn + ni*16 + n;
    float bsv = bias[col];
    #pragma unroll
    for (int rg=0; rg<4; rg++){
      int row = m0 + wm + mi*16 + quad*4 + rg;
      float v = acc[mi][ni][rg] + bsv;
      if (GELU) v = gelu_f(v);
      if (OUTF32) ((float*)Cp)[(size_t)row*N + col] = v;
      else ((unsigned short*)Cp)[(size_t)row*N + col] = f2bf(v);
    }
  }
}

// ---------------- GEMM 256x256xBK64, 2-phase one-barrier pipeline (T3 minimum) ----
// Order per K-tile: {stage(next) -> ds_read(cur) -> MFMA -> vmcnt(0) -> barrier}.
// Prefetch overlaps the full compute phase; one barrier per tile (race-free: a wave
// passes barrier(kt-1) only after vmcnt(0) drained its stage(kt); all waves' ds_reads
// of a buffer complete before their own barrier arrival). Anchor: m248v2 666-682 TF.
template<int OUTF32, int GELU>
__global__ __launch_bounds__(512) void gemm256(const unsigned short* __restrict__ A,
    const unsigned short* __restrict__ BT, const float* __restrict__ bias,
    void* __restrict__ Cp, int M, int N, int K){
  __shared__ unsigned short AsB[2][256*64];
  __shared__ unsigned short BsB[2][256*64];
  const int tid = threadIdx.x;
  const int gx = gridDim.x;
  const int nwg = gx * gridDim.y;
  const int wg = xcd_swz(blockIdx.y*gx + blockIdx.x, nwg);
  const int m0 = (wg / gx) * 256, n0 = (wg % gx) * 256;
  const int lane = tid & 63, w = tid >> 6;
  const int n = lane & 15, quad = lane >> 4;
  const int wm = (w>>2)*128, wn = (w&3)*64;
  const int lr = lane >> 3, site = lane & 7;
  const int NK = K >> 6;
  f32x4 acc[8][4] = {};

  auto stage = [&](int b, int kb){
    #pragma unroll
    for (int j=0;j<4;j++){
      int rbase = w*32 + j*8;
      int r = rbase + lr;
      int q = site ^ (r & 7);
      gld_lds16(A  + (size_t)(m0+r)*K + kb + q*8, &AsB[b][rbase*64]);
      gld_lds16(BT + (size_t)(n0+r)*K + kb + q*8, &BsB[b][rbase*64]);
    }
  };

  // prologue: stage tile 0, drain, barrier
  stage(0, 0);
  asm volatile("s_waitcnt vmcnt(0)" ::: "memory");
  __builtin_amdgcn_s_barrier();

  int cur = 0;
  for (int kt=0; kt<NK; ++kt){
    if (kt+1 < NK) stage(cur^1, (kt+1)<<6);     // issue next-tile loads FIRST
    const unsigned short* As_ = AsB[cur];
    const unsigned short* Bs_ = BsB[cur];
    bf16x8 bfr[2][4];
    #pragma unroll
    for (int ks=0;ks<2;ks++)
    #pragma unroll
    for (int ni=0;ni<4;ni++){
      int rn = wn + ni*16 + n;
      bfr[ks][ni] = *(const bf16x8*)&Bs_[rn*64 + (((ks*4+quad) ^ (rn&7))<<3)];
    }
    #pragma unroll
    for (int mi=0;mi<8;mi++){
      int rm = wm + mi*16 + n;
      bf16x8 a0 = *(const bf16x8*)&As_[rm*64 + (((quad)     ^ (rm&7))<<3)];
      bf16x8 a1 = *(const bf16x8*)&As_[rm*64 + (((4+quad)   ^ (rm&7))<<3)];
      #pragma unroll
      for (int ni=0;ni<4;ni++)
        acc[mi][ni] = __builtin_amdgcn_mfma_f32_16x16x32_bf16(a0, bfr[0][ni], acc[mi][ni],0,0,0);
      #pragma unroll
      for (int ni=0;ni<4;ni++)
        acc[mi][ni] = __builtin_amdgcn_mfma_f32_16x16x32_bf16(a1, bfr[1][ni], acc[mi][ni],0,0,0);
    }
    if (kt+1 < NK){
      asm volatile("s_waitcnt vmcnt(0)" ::: "memory");   // next tile landed
      __builtin_amdgcn_s_barrier();                      // one barrier per tile
    }
    cur ^= 1;
  }
  #pragma unroll
  for (int mi=0;mi<8;mi++)
  #pragma unroll
  for (int ni=0;ni<4;ni++){
    int col = n0 + wn + ni*16 + n;
    float bsv = bias[col];
    #pragma unroll
    for (int rg=0;rg<4;rg++){
      int row = m0 + wm + mi*16 + quad*4 + rg;
      float v = acc[mi][ni][rg] + bsv;
      if (GELU) v = gelu_f(v);
      if (OUTF32) ((float*)Cp)[(size_t)row*N + col] = v;
      else ((unsigned short*)Cp)[(size_t)row*N + col] = f2bf(v);
    }
  }
}

// ---------------- MFMA banded sliding-window attention (+ global key column) ----------------
// qkv: fused [NBS, 3840] bf16 with columns [q|k|v|kg|vg]
__global__ __launch_bounds__(256, 2) void band_attn_mfma(
    const unsigned short* __restrict__ qkv, const int* __restrict__ am,
    unsigned short* __restrict__ Out){
  __shared__ unsigned short Kt[64*72];        // [key][dim], pad 72
  __shared__ unsigned short Vt[64*72];        // [dim][key], pad 72 (transposed)
  __shared__ unsigned short Pbuf[4*64*72];    // per-wave P tile [q][key], pad 72
  __shared__ float mk[64];                    // per-key additive mask (0 / -1e9)
  __shared__ unsigned short kgs[64];
  __shared__ unsigned short vgs[64];

  const int tid = threadIdx.x;
  const int bid = xcd_swz(blockIdx.x, gridDim.x);
  const int c = bid & (NCHUNK-1);
  const int h = (bid / NCHUNK) % NHEAD;
  const int b = bid / (NCHUNK*NHEAD);
  const int lane = tid & 63, w = tid >> 6;
  const int n = lane & 15, quad = lane >> 4;
  const int qbase = w * 64;
  unsigned short* Pw = Pbuf + w*64*72;

  if (tid < 8)       ((uint4*)kgs)[tid]   = ((const uint4*)(qkv + ((size_t)b*NS)*QSTR + OKG + h*DHEAD))[tid];
  else if (tid < 16) ((uint4*)vgs)[tid-8] = ((const uint4*)(qkv + ((size_t)b*NS)*QSTR + OVG + h*DHEAD))[tid-8];
  __syncthreads();

  bf16x8 aQ[4][2];
  #pragma unroll
  for (int mi=0; mi<4; mi++)
  #pragma unroll
  for (int ks=0; ks<2; ks++)
    aQ[mi][ks] = *(const bf16x8*)(qkv + ((size_t)(b*NS + c*WWIN + qbase + 16*mi + n))*QSTR
                                    + OQ + h*DHEAD + ks*32 + quad*8);

  f32x4 sacc[4] = {};
  #pragma unroll
  for (int ks=0; ks<2; ks++){
    bf16x8 bg = *(const bf16x8*)(kgs + ks*32 + quad*8);
    bf16x8 z8 = {};
    bg = (n == 0) ? bg : z8;
    #pragma unroll
    for (int mi=0; mi<4; mi++)
      sacc[mi] = __builtin_amdgcn_mfma_f32_16x16x32_bf16(aQ[mi][ks], bg, sacc[mi], 0,0,0);
  }
  float mst[4][4], lpt[4][4];
  f32x4 apv[4][4];
  float vgf[4];
  #pragma unroll
  for (int ni=0; ni<4; ni++) vgf[ni] = bf2f(vgs[16*ni + n]);
  #pragma unroll
  for (int mi=0; mi<4; mi++)
  #pragma unroll
  for (int rg=0; rg<4; rg++){
    float sg = __shfl(sacc[mi][rg], lane & 48);
    mst[mi][rg] = sg * 0.125f;
    lpt[mi][rg] = (n == 0) ? 1.0f : 0.0f;
  }
  #pragma unroll
  for (int mi=0; mi<4; mi++)
  #pragma unroll
  for (int ni=0; ni<4; ni++)
  #pragma unroll
  for (int rg=0; rg<4; rg++) apv[mi][ni][rg] = vgf[ni];

  for (int t=0; t<12; t++){
    __syncthreads();
    {
      int i = tid >> 2, d0 = (tid & 3) * 8;
      int kp = (c-1)*WWIN + t*64 + i;
      int kpc = min(max(kp, 0), NS-1);
      size_t gb = ((size_t)(b*NS + kpc))*QSTR + h*DHEAD;
      uint4 k0 = *(const uint4*)(qkv + gb + OK_ + d0);
      uint4 k1 = *(const uint4*)(qkv + gb + OK_ + d0 + 32);
      uint4 v0 = *(const uint4*)(qkv + gb + OV + d0);
      uint4 v1 = *(const uint4*)(qkv + gb + OV + d0 + 32);
      *(uint4*)(Kt + i*72 + d0) = k0;
      *(uint4*)(Kt + i*72 + d0 + 32) = k1;
      const unsigned short* s0 = (const unsigned short*)&v0;
      const unsigned short* s1 = (const unsigned short*)&v1;
      #pragma unroll
      for (int j=0;j<8;j++){
        Vt[(d0+j)*72 + i] = s0[j];
        Vt[(d0+32+j)*72 + i] = s1[j];
      }
      if ((tid & 3) == 0)
        mk[i] = (kp >= 1 && kp < NS && am[b*NS + kpc] > 0) ? 0.0f : -1e9f;
    }
    __syncthreads();

    float mkv[4];
    #pragma unroll
    for (int ni=0; ni<4; ni++) mkv[ni] = mk[16*ni + n];

    f32x4 accs[4][4] = {};
    #pragma unroll
    for (int ks=0; ks<2; ks++){
      bf16x8 bK[4];
      #pragma unroll
      for (int ni=0; ni<4; ni++)
        bK[ni] = *(const bf16x8*)(Kt + (16*ni + n)*72 + ks*32 + quad*8);
      #pragma unroll
      for (int mi=0; mi<4; mi++)
      #pragma unroll
      for (int ni=0; ni<4; ni++)
        accs[mi][ni] = __builtin_amdgcn_mfma_f32_16x16x32_bf16(aQ[mi][ks], bK[ni], accs[mi][ni], 0,0,0);
    }

    #pragma unroll
    for (int mi=0; mi<4; mi++){
      float sv[4][4];
      #pragma unroll
      for (int ni=0; ni<4; ni++)
      #pragma unroll
      for (int rg=0; rg<4; rg++){
        int kk = t*64 + 16*ni + n;
        int pr = qbase + 16*mi + quad*4 + rg;
        float s = accs[mi][ni][rg]*0.125f + mkv[ni];
        if ((unsigned)(kk - pr) > 512u) s = -1e9f;
        sv[ni][rg] = s;
      }
      #pragma unroll
      for (int rg=0; rg<4; rg++){
        float rm = fmaxf(fmaxf(sv[0][rg], sv[1][rg]), fmaxf(sv[2][rg], sv[3][rg]));
        rm = rowmax16(rm);
        float mold = mst[mi][rg];
        float mnew = fmaxf(mold, rm);
        float alpha = __expf(mold - mnew);
        mst[mi][rg] = mnew;
        float psum = 0.f;
        #pragma unroll
        for (int ni=0; ni<4; ni++){
          float pv = __expf(sv[ni][rg] - mnew);
          sv[ni][rg] = pv;
          psum += pv;
        }
        lpt[mi][rg] = lpt[mi][rg]*alpha + psum;
        #pragma unroll
        for (int ni=0; ni<4; ni++) apv[mi][ni][rg] *= alpha;
        int prow = 16*mi + quad*4 + rg;
        #pragma unroll
        for (int ni=0; ni<4; ni++)
          Pw[prow*72 + 16*ni + n] = f2bf(sv[ni][rg]);
      }
    }

    #pragma unroll
    for (int ks2=0; ks2<2; ks2++){
      bf16x8 aP[4], bV[4];
      #pragma unroll
      for (int mi=0; mi<4; mi++)
        aP[mi] = *(const bf16x8*)(Pw + (16*mi + n)*72 + ks2*32 + quad*8);
      #pragma unroll
      for (int ni=0; ni<4; ni++)
        bV[ni] = *(const bf16x8*)(Vt + (16*ni + n)*72 + ks2*32 + quad*8);
      #pragma unroll
      for (int mi=0; mi<4; mi++)
      #pragma unroll
      for (int ni=0; ni<4; ni++)
        apv[mi][ni] = __builtin_amdgcn_mfma_f32_16x16x32_bf16(aP[mi], bV[ni], apv[mi][ni], 0,0,0);
    }
  }

  #pragma unroll
  for (int mi=0; mi<4; mi++)
  #pragma unroll
  for (int rg=0; rg<4; rg++){
    float L = rowsum16(lpt[mi][rg]);
    float inv = 1.0f / L;
    int q = c*WWIN + qbase + 16*mi + quad*4 + rg;
    size_t ob = ((size_t)(b*NS + q))*HIDN + h*DHEAD;
    #pragma unroll
    for (int ni=0; ni<4; ni++)
      Out[ob + 16*ni + n] = f2bf(apv[mi][ni][rg] * inv);
  }
}

// ---------------- split-flash global (CLS) attention: partials over 128-key chunks ----
__global__ __launch_bounds__(128) void gattn_part(
    const unsigned short* __restrict__ QG0, const unsigned short* __restrict__ qkv,
    const int* __restrict__ am, float* __restrict__ part){
  __shared__ float qs[64];
  __shared__ float ps[128];
  __shared__ float red[128];
  int t = threadIdx.x;
  int cx = blockIdx.x, h = blockIdx.y, b = blockIdx.z;
  if (t < 32){
    float a, bb; unpack2(((const unsigned int*)(QG0 + (size_t)b*128*HIDN + h*DHEAD))[t], a, bb);
    qs[2*t]=a*0.125f; qs[2*t+1]=bb*0.125f;
  }
  __syncthreads();
  int kp = cx*128 + t;
  const unsigned int* kr = (const unsigned int*)(qkv + ((size_t)(b*NS+kp))*QSTR + OKG + h*DHEAD);
  float sv = 0.f;
  #pragma unroll
  for (int j=0;j<32;j++){ float a,bb; unpack2(kr[j],a,bb); sv += qs[2*j]*a + qs[2*j+1]*bb; }
  if (am[b*NS+kp] <= 0) sv = -1e9f;
  red[t] = sv; __syncthreads();
  for (int st=64; st>0; st>>=1){ if (t<st) red[t] = fmaxf(red[t], red[t+st]); __syncthreads(); }
  float M = red[0]; __syncthreads();
  float e = __expf(sv - M);
  ps[t] = e; red[t] = e; __syncthreads();
  for (int st=64; st>0; st>>=1){ if (t<st) red[t] += red[t+st]; __syncthreads(); }
  float L = red[0];
  float* po = part + ((size_t)((b*NHEAD+h)*32 + cx))*66;
  if (t==0){ po[0]=M; po[1]=L; }
  if (t < 64){
    float o = 0.f;
    #pragma unroll 4
    for (int i=0;i<128;i++)
      o += ps[i] * bf2f(qkv[((size_t)(b*NS + cx*128 + i))*QSTR + OVG + h*DHEAD + t]);
    po[2+t] = o;
  }
}

__global__ __launch_bounds__(64) void gattn_reduce(const float* __restrict__ part,
    unsigned short* __restrict__ Out){
  int bh = blockIdx.x;
  int b = bh / NHEAD, h = bh % NHEAD;
  int d = threadIdx.x;
  const float* pp = part + (size_t)bh*32*66;
  float M = -1e30f;
  for (int c2=0;c2<32;c2++) M = fmaxf(M, pp[c2*66]);
  float L = 0.f, o = 0.f;
  for (int c2=0;c2<32;c2++){
    float w = __expf(pp[c2*66] - M);
    L += pp[c2*66+1]*w;
    o += pp[c2*66+2+d]*w;
  }
  Out[((size_t)b*NS)*HIDN + h*DHEAD + d] = f2bf(o / L);
}

// ---------------- classification head on CLS token (all fp32), 4-way d-split ----
__global__ __launch_bounds__(256) void head_k(const float* __restrict__ X,
    const float* __restrict__ HW, const float* __restrict__ HB,
    float* __restrict__ Outp){
  __shared__ float red[256];
  __shared__ float xs[HIDN];
  int b = blockIdx.y;
  int base = blockIdx.x*64;
  int t = threadIdx.x;
  const float* x0 = X + (size_t)b*NS*HIDN;
  for (int i=t; i<HIDN; i+=256) xs[i] = x0[i];
  __syncthreads();
  int n = base + (t & 63);
  int dp = t >> 6;             // 0..3, 192 dims each
  float a = 0.f;
  if (n < NLABEL){
    #pragma unroll 4
    for (int d=dp*192; d<dp*192+192; ++d)
      a += xs[d] * HW[(size_t)d*NLABEL + n];
  }
  red[t] = a; __syncthreads();
  if (t < 64 && n < NLABEL)
    Outp[(size_t)b*NLABEL + n] = red[t]+red[t+64]+red[t+128]+red[t+192] + HB[n];
}

extern "C" void kernel_launch(void* const* d_in, const int* in_sizes, int n_in,
                              void* d_out, int out_size, void* d_ws, size_t ws_size,
                              hipStream_t stream){
  (void)in_sizes; (void)n_in; (void)out_size; (void)ws_size;
  const int* ids = (const int*)d_in[0];
  const int* am  = (const int*)d_in[1];
  const float* we  = (const float*)d_in[2];
  const float* pe  = (const float*)d_in[3];
  const float* elns= (const float*)d_in[4];
  const float* elnb= (const float*)d_in[5];
  const float* Wq  = (const float*)d_in[6];
  const float* bq  = (const float*)d_in[7];
  const float* Wk  = (const float*)d_in[8];
  const float* bk  = (const float*)d_in[9];
  const float* Wv  = (const float*)d_in[10];
  const float* bv  = (const float*)d_in[11];
  const float* Wqg = (const float*)d_in[12];
  const float* bqg = (const float*)d_in[13];
  const float* Wkg = (const float*)d_in[14];
  const float* bkg = (const float*)d_in[15];
  const float* Wvg = (const float*)d_in[16];
  const float* bvg = (const float*)d_in[17];
  const float* Wo  = (const float*)d_in[18];
  const float* bo  = (const float*)d_in[19];
  const float* l1s = (const float*)d_in[20];
  const float* l1b = (const float*)d_in[21];
  const float* W1  = (const float*)d_in[22];
  const float* b1  = (const float*)d_in[23];
  const float* W2  = (const float*)d_in[24];
  const float* b2  = (const float*)d_in[25];
  const float* l2s = (const float*)d_in[26];
  const float* l2b = (const float*)d_in[27];
  const float* hW  = (const float*)d_in[28];
  const float* hB  = (const float*)d_in[29];

  char* ws = (char*)d_ws;
  float* x = (float*)ws;                                    // 25,165,824 B
  float* y = (float*)(ws + 25165824);                       // 25,165,824 B
  unsigned short* xb   = (unsigned short*)(ws + 50331648);  // 12,582,912 B
  unsigned short* qkvb = (unsigned short*)(ws + 62914560);  // 8192*3840*2 = 62,914,560 B
  unsigned short* qg0b = (unsigned short*)(ws + 125829120); // 393,216 B
  float* part = (float*)(ws + 126222336);                   // 202,752 B
  unsigned short* ao   = (unsigned short*)(ws + 126425088); // 12,582,912 B
  unsigned short* hbuf = (unsigned short*)(ws + 139008000); // 50,331,648 B
  unsigned short* wt   = (unsigned short*)(ws + 189339648); // 35,389,440 B
  float* bpack = (float*)(ws + 224729088);                  // 2*3840*4 = 30,720 B

  const size_t SQ = 589824;        // 768*768
  const size_t SW = 2359296;       // 768*3072
  const size_t PERL = 7*SQ + 2*SW;

  auto tr = [&](const float* src, unsigned short* dst, int R, int C){
    dim3 g(C/32, R/32), blk(32, 8);
    transpose_k<<<g, blk, 0, stream>>>(src, dst, R, C);
  };
  // layout per layer: [q | k | v | kg | vg] (fused N=3840), then qg, o, W1, W2
  for (int l=0; l<NLAYER; l++){
    unsigned short* base = wt + (size_t)l*PERL;
    tr(Wq  + (size_t)l*SQ, base + 0*SQ, 768, 768);
    tr(Wk  + (size_t)l*SQ, base + 1*SQ, 768, 768);
    tr(Wv  + (size_t)l*SQ, base + 2*SQ, 768, 768);
    tr(Wkg + (size_t)l*SQ, base + 3*SQ, 768, 768);
    tr(Wvg + (size_t)l*SQ, base + 4*SQ, 768, 768);
    tr(Wqg + (size_t)l*SQ, base + 5*SQ, 768, 768);
    tr(Wo  + (size_t)l*SQ, base + 6*SQ, 768, 768);
    tr(W1  + (size_t)l*SW, base + 7*SQ, 768, 3072);
    tr(W2  + (size_t)l*SW, base + 7*SQ + SW, 3072, 768);
  }
  pack_bias_k<<<(NLAYER*QSTR)/256, 256, 0, stream>>>(bq, bk, bv, bkg, bvg, bpack);

  embed_k<<<(NBS*HIDN)/256, 256, 0, stream>>>(ids, we, pe, y);
  ln_k<<<NBS, 256, 0, stream>>>(y, nullptr, elns, elnb, x, xb);

  for (int l=0; l<NLAYER; l++){
    unsigned short* base = wt + (size_t)l*PERL;
    // fused q/k/v/kg/vg projection: N = 5*768 = 3840 at 256^2 tiles: 15x32 = 480 blocks
    gemm256<0,0><<<dim3(15,32), 512, 0, stream>>>(xb, base, bpack + (size_t)l*QSTR,
                                                  qkvb, NBS, QSTR, 768);
    // qg needed only for CLS row: project first 128 rows of each batch
    for (int b=0; b<NB; b++)
      gemm128<0,0><<<dim3(6,1), 256, 0, stream>>>(xb + (size_t)b*NS*HIDN, base + 5*SQ,
                                                  bqg + l*768, qg0b + (size_t)b*128*HIDN,
                                                  128, 768, 768);
    band_attn_mfma<<<NB*NHEAD*NCHUNK, 256, 0, stream>>>(qkvb, am, ao);
    gattn_part<<<dim3(32, NHEAD, NB), 128, 0, stream>>>(qg0b, qkvb, am, part);
    gattn_reduce<<<NB*NHEAD, 64, 0, stream>>>(part, ao);
    gemm128<1,0><<<dim3(6,64), 256, 0, stream>>>(ao, base + 6*SQ, bo + l*768, y, NBS, 768, 768);
    ln_k<<<NBS, 256, 0, stream>>>(y, x, l1s + l*768, l1b + l*768, x, xb);
    // FFN1 at 256^2: 12x32 = 384 blocks
    gemm256<0,1><<<dim3(12,32), 512, 0, stream>>>(xb, base + 7*SQ, b1 + l*3072, hbuf, NBS, 3072, 768);
    gemm128<1,0><<<dim3(6,64), 256, 0, stream>>>(hbuf, base + 7*SQ + SW, b2 + l*768, y, NBS, 768, 3072);
    ln_k<<<NBS, 256, 0, stream>>>(y, x, l2s + l*768, l2b + l*768, x, xb);
  }

  head_k<<<dim3((NLABEL+63)/64, NB), 256, 0, stream>>>(x, hW, hB, (float*)d_out);
}

// Round 5
// 1120.554 us; speedup vs baseline: 1.1615x; 1.0393x over previous
//
#include <hip/hip_runtime.h>
#include <hip/hip_bf16.h>
#include <math.h>

// ---- model dims ----
#define HIDN 768
#define NHEAD 12
#define DHEAD 64
#define WWIN 256
#define NCHUNK 16
#define NLAYER 2
#define FFND 3072
#define NLABEL 8921
#define NB 2
#define NS 4096
#define NBS (NB*NS)

// fused projection output: [q | k | v | kg | vg] along N
#define QSTR 3840
#define OQ   0
#define OK_  768
#define OV   1536
#define OKG  2304
#define OVG  3072

typedef __attribute__((ext_vector_type(8))) short bf16x8;
typedef __attribute__((ext_vector_type(4))) float f32x4;

__device__ __forceinline__ float bf2f(unsigned short u){
  union { unsigned int i; float f; } v; v.i = ((unsigned int)u) << 16; return v.f;
}
__device__ __forceinline__ unsigned short f2bf(float f){
  __hip_bfloat16 h = __float2bfloat16(f);
  return *reinterpret_cast<unsigned short*>(&h);
}
__device__ __forceinline__ void unpack2(unsigned int u, float& a, float& b){
  union { unsigned int i; float f; } x, y;
  x.i = u << 16; y.i = u & 0xffff0000u; a = x.f; b = y.f;
}
// exact-GELU via A&S 7.1.26 erf approximation (|err| < 1.5e-7), no libcall
__device__ __forceinline__ float gelu_f(float v){
  float x = v * 0.70710678118f;
  float ax = fabsf(x);
  float t = 1.0f / (1.0f + 0.3275911f*ax);
  float poly = ((((1.061405429f*t - 1.453152027f)*t + 1.421413741f)*t
                - 0.284496736f)*t + 0.254829592f)*t;
  float y = 1.0f - poly*__expf(-x*x);
  float er = copysignf(y, x);
  return 0.5f*v*(1.0f + er);
}
// async global->LDS, 16B per lane; LDS dest = ldsbase + lane*16
__device__ __forceinline__ void gld_lds16(const unsigned short* g, unsigned short* l){
  __builtin_amdgcn_global_load_lds((const __attribute__((address_space(1))) unsigned int*)g,
                                   (__attribute__((address_space(3))) unsigned int*)l, 16, 0, 0);
}

// bijective XCD-chunked swizzle of a linear block id (m204 variant)
__device__ __forceinline__ int xcd_swz(int orig, int nwg){
  int q = nwg >> 3, r = nwg & 7;
  int x = orig & 7, lo = orig >> 3;
  return (x < r ? x*(q+1) : r*(q+1) + (x-r)*q) + lo;
}

// DPP row-rotate helper: rotate within 16-lane row by N, combine for reductions.
#define DPP_ROR_F(x, N) __builtin_bit_cast(float, __builtin_amdgcn_update_dpp( \
    0, __builtin_bit_cast(int, (x)), 0x120 + (N), 0xf, 0xf, true))
__device__ __forceinline__ float rowmax16(float x){
  x = fmaxf(x, DPP_ROR_F(x, 1));
  x = fmaxf(x, DPP_ROR_F(x, 2));
  x = fmaxf(x, DPP_ROR_F(x, 4));
  x = fmaxf(x, DPP_ROR_F(x, 8));
  return x;
}
__device__ __forceinline__ float rowsum16(float x){
  x = x + DPP_ROR_F(x, 1);
  x = x + DPP_ROR_F(x, 2);
  x = x + DPP_ROR_F(x, 4);
  x = x + DPP_ROR_F(x, 8);
  return x;
}

// ---------------- embedding (fp32 inputs) ----------------
__global__ __launch_bounds__(256) void embed_k(const int* __restrict__ ids,
    const float* __restrict__ we, const float* __restrict__ pe,
    float* __restrict__ y){
  int i = blockIdx.x*256 + threadIdx.x;
  int row = i / HIDN; int d = i - row*HIDN;
  int s = row & (NS-1);
  int id = ids[row];
  y[i] = we[(size_t)id*HIDN + d] + pe[(size_t)s*HIDN + d];
}

// ---------------- layernorm (optional residual), fp32 + bf16 outputs ----------------
__global__ __launch_bounds__(256) void ln_k(const float* A, const float* R,
    const float* __restrict__ sc, const float* __restrict__ bi,
    float* X, unsigned short* XB){
  __shared__ float red[256];
  int row = blockIdx.x, t = threadIdx.x;
  size_t base = (size_t)row*HIDN;
  float v0 = A[base+t], v1 = A[base+t+256], v2 = A[base+t+512];
  if (R){ v0 += R[base+t]; v1 += R[base+t+256]; v2 += R[base+t+512]; }
  red[t] = v0+v1+v2; __syncthreads();
  for (int st=128; st>0; st>>=1){ if (t<st) red[t]+=red[t+st]; __syncthreads(); }
  float mean = red[0] * (1.0f/HIDN); __syncthreads();
  float d0=v0-mean, d1=v1-mean, d2=v2-mean;
  red[t] = d0*d0+d1*d1+d2*d2; __syncthreads();
  for (int st=128; st>0; st>>=1){ if (t<st) red[t]+=red[t+st]; __syncthreads(); }
  float rs = rsqrtf(red[0] * (1.0f/HIDN) + 1e-5f);
  float o0 = d0*rs*sc[t]     + bi[t];
  float o1 = d1*rs*sc[t+256] + bi[t+256];
  float o2 = d2*rs*sc[t+512] + bi[t+512];
  X[base+t]=o0; X[base+t+256]=o1; X[base+t+512]=o2;
  XB[base+t]=f2bf(o0); XB[base+t+256]=f2bf(o1); XB[base+t+512]=f2bf(o2);
}

// ---------------- fused fp32 [R,C] -> bf16 transpose [C,R] over 18 weight mats ----
struct TrTable {
  const float* src[18];
  unsigned short* dst[18];
  int R[18]; int C[18];
  int t0[19];          // prefix sums of tile counts
};
__global__ __launch_bounds__(256) void transpose_all_k(TrTable tt){
  __shared__ unsigned short tile[32][33];
  int bid = blockIdx.x;
  int m = 0;
  #pragma unroll 1
  while (bid >= tt.t0[m+1]) m++;
  int local = bid - tt.t0[m];
  int C = tt.C[m], R = tt.R[m];
  int Ct = C >> 5;
  int ct = (local % Ct) * 32, rt = (local / Ct) * 32;
  const float* src = tt.src[m];
  unsigned short* dst = tt.dst[m];
  int tx = threadIdx.x, ty = threadIdx.y;     // 32 x 8
  #pragma unroll
  for (int i=0;i<4;i++) tile[ty+i*8][tx] = f2bf(src[(size_t)(rt+ty+i*8)*C + ct + tx]);
  __syncthreads();
  #pragma unroll
  for (int i=0;i<4;i++) dst[(size_t)(ct+ty+i*8)*R + rt + tx] = tile[tx][ty+i*8];
}

// ---------------- bias concat for fused qkv/kg/vg projection ----------------
__global__ __launch_bounds__(256) void pack_bias_k(const float* __restrict__ bq,
    const float* __restrict__ bk, const float* __restrict__ bv,
    const float* __restrict__ bkg, const float* __restrict__ bvg,
    float* __restrict__ out){
  int i = blockIdx.x*256 + threadIdx.x;      // 0 .. NLAYER*3840-1
  int l = i / QSTR; int j = i - l*QSTR;
  int seg = j / HIDN, d = j - seg*HIDN;
  const float* src = (seg==0)?bq : (seg==1)?bk : (seg==2)?bv : (seg==3)?bkg : bvg;
  out[i] = src[l*HIDN + d];
}

// ---------------- GEMM 128x128xBK64, global_load_lds staging, XOR-swizzled LDS ----
// C[M,N] = A[M,K](bf16) * BT[N,K]^T (bf16) + bias(fp32). M%128==0, N%128==0, K%64==0.
template<int OUTF32, int GELU>
__global__ __launch_bounds__(256) void gemm128(const unsigned short* __restrict__ A,
    const unsigned short* __restrict__ BT, const float* __restrict__ bias,
    void* __restrict__ Cp, int M, int N, int K){
  __shared__ unsigned short As[128*64];
  __shared__ unsigned short Bs[128*64];
  const int tid = threadIdx.x;
  const int nwg = gridDim.x * gridDim.y;
  const int wg = xcd_swz(blockIdx.y * gridDim.x + blockIdx.x, nwg);
  const int m0 = (wg / gridDim.x) * 128, n0 = (wg % gridDim.x) * 128;
  const int lane = tid & 63, w = tid >> 6;
  const int n = lane & 15, quad = lane >> 4;
  const int wm = (w>>1)*64, wn = (w&1)*64;
  const int lr = lane >> 3, site = lane & 7;   // staging: 8 rows x 8 sites per instr
  f32x4 acc[4][4] = {};
  for (int kb=0; kb<K; kb+=64){
    #pragma unroll
    for (int j=0;j<4;j++){
      int rbase = w*32 + j*8;
      int r = rbase + lr;
      int q = site ^ (r & 7);
      gld_lds16(A  + (size_t)(m0+r)*K + kb + q*8, &As[rbase*64]);
      gld_lds16(BT + (size_t)(n0+r)*K + kb + q*8, &Bs[rbase*64]);
    }
    __syncthreads();
    #pragma unroll
    for (int ks=0; ks<2; ks++){
      bf16x8 a[4], b[4];
      #pragma unroll
      for (int i=0;i<4;i++){
        int rm = wm + i*16 + n;
        a[i] = *(const bf16x8*)&As[rm*64 + (((ks*4+quad) ^ (rm&7))<<3)];
        int rn = wn + i*16 + n;
        b[i] = *(const bf16x8*)&Bs[rn*64 + (((ks*4+quad) ^ (rn&7))<<3)];
      }
      #pragma unroll
      for (int mi=0;mi<4;mi++)
      #pragma unroll
      for (int ni=0;ni<4;ni++)
        acc[mi][ni] = __builtin_amdgcn_mfma_f32_16x16x32_bf16(a[mi], b[ni], acc[mi][ni], 0,0,0);
    }
    __syncthreads();
  }
  #pragma unroll
  for (int mi=0; mi<4; mi++)
  #pragma unroll
  for (int ni=0; ni<4; ni++){
    int col = n0 + wn + ni*16 + n;
    float bsv = bias[col];
    #pragma unroll
    for (int rg=0; rg<4; rg++){
      int row = m0 + wm + mi*16 + quad*4 + rg;
      float v = acc[mi][ni][rg] + bsv;
      if (GELU) v = gelu_f(v);
      if (OUTF32) ((float*)Cp)[(size_t)row*N + col] = v;
      else ((unsigned short*)Cp)[(size_t)row*N + col] = f2bf(v);
    }
  }
}

// ---------------- qg projection for CLS rows of both batches in one launch ----
// M=128 per batch, N=768, K=768. blockIdx.z = batch.
__global__ __launch_bounds__(256) void gemm128qg(const unsigned short* __restrict__ A0,
    const unsigned short* __restrict__ BT, const float* __restrict__ bias,
    unsigned short* __restrict__ C0){
  __shared__ unsigned short As[128*64];
  __shared__ unsigned short Bs[128*64];
  const unsigned short* A = A0 + (size_t)blockIdx.z*NS*HIDN;
  unsigned short* C = C0 + (size_t)blockIdx.z*128*HIDN;
  const int K = 768, N = 768;
  const int tid = threadIdx.x;
  const int n0 = blockIdx.x * 128;
  const int lane = tid & 63, w = tid >> 6;
  const int n = lane & 15, quad = lane >> 4;
  const int wm = (w>>1)*64, wn = (w&1)*64;
  const int lr = lane >> 3, site = lane & 7;
  f32x4 acc[4][4] = {};
  for (int kb=0; kb<K; kb+=64){
    #pragma unroll
    for (int j=0;j<4;j++){
      int rbase = w*32 + j*8;
      int r = rbase + lr;
      int q = site ^ (r & 7);
      gld_lds16(A  + (size_t)r*K + kb + q*8, &As[rbase*64]);
      gld_lds16(BT + (size_t)(n0+r)*K + kb + q*8, &Bs[rbase*64]);
    }
    __syncthreads();
    #pragma unroll
    for (int ks=0; ks<2; ks++){
      bf16x8 a[4], b[4];
      #pragma unroll
      for (int i=0;i<4;i++){
        int rm = wm + i*16 + n;
        a[i] = *(const bf16x8*)&As[rm*64 + (((ks*4+quad) ^ (rm&7))<<3)];
        int rn = wn + i*16 + n;
        b[i] = *(const bf16x8*)&Bs[rn*64 + (((ks*4+quad) ^ (rn&7))<<3)];
      }
      #pragma unroll
      for (int mi=0;mi<4;mi++)
      #pragma unroll
      for (int ni=0;ni<4;ni++)
        acc[mi][ni] = __builtin_amdgcn_mfma_f32_16x16x32_bf16(a[mi], b[ni], acc[mi][ni], 0,0,0);
    }
    __syncthreads();
  }
  #pragma unroll
  for (int mi=0; mi<4; mi++)
  #pragma unroll
  for (int ni=0; ni<4; ni++){
    int col = n0 + wn + ni*16 + n;
    float bsv = bias[col];
    #pragma unroll
    for (int rg=0; rg<4; rg++){
      int row = wm + mi*16 + quad*4 + rg;
      C[(size_t)row*N + col] = f2bf(acc[mi][ni][rg] + bsv);
    }
  }
}

// ---------------- GEMM 256x256xBK64, SINGLE-buffer LDS (64 KiB) -> 2 blocks/CU ----
// m97-style sync: {stage -> syncthreads -> ds_read+MFMA (setprio) -> syncthreads}.
// Cross-block TLP (2 blocks/CU, 16 waves) hides the vmcnt drain; grids <= 512
// blocks are fully co-resident (no dispatch tail).
template<int OUTF32, int GELU>
__global__ __launch_bounds__(512) void gemm256(const unsigned short* __restrict__ A,
    const unsigned short* __restrict__ BT, const float* __restrict__ bias,
    void* __restrict__ Cp, int M, int N, int K){
  __shared__ unsigned short As[256*64];
  __shared__ unsigned short Bs[256*64];
  const int tid = threadIdx.x;
  const int gx = gridDim.x;
  const int nwg = gx * gridDim.y;
  const int wg = xcd_swz(blockIdx.y*gx + blockIdx.x, nwg);
  const int m0 = (wg / gx) * 256, n0 = (wg % gx) * 256;
  const int lane = tid & 63, w = tid >> 6;
  const int n = lane & 15, quad = lane >> 4;
  const int wm = (w>>2)*128, wn = (w&3)*64;
  const int lr = lane >> 3, site = lane & 7;
  f32x4 acc[8][4] = {};

  for (int kb=0; kb<K; kb+=64){
    #pragma unroll
    for (int j=0;j<4;j++){
      int rbase = w*32 + j*8;
      int r = rbase + lr;
      int q = site ^ (r & 7);
      gld_lds16(A  + (size_t)(m0+r)*K + kb + q*8, &As[rbase*64]);
      gld_lds16(BT + (size_t)(n0+r)*K + kb + q*8, &Bs[rbase*64]);
    }
    __syncthreads();
    bf16x8 bfr[2][4];
    #pragma unroll
    for (int ks=0;ks<2;ks++)
    #pragma unroll
    for (int ni=0;ni<4;ni++){
      int rn = wn + ni*16 + n;
      bfr[ks][ni] = *(const bf16x8*)&Bs[rn*64 + (((ks*4+quad) ^ (rn&7))<<3)];
    }
    __builtin_amdgcn_s_setprio(1);
    #pragma unroll
    for (int mi=0;mi<8;mi++){
      int rm = wm + mi*16 + n;
      bf16x8 a0 = *(const bf16x8*)&As[rm*64 + (((quad)     ^ (rm&7))<<3)];
      bf16x8 a1 = *(const bf16x8*)&As[rm*64 + (((4+quad)   ^ (rm&7))<<3)];
      #pragma unroll
      for (int ni=0;ni<4;ni++)
        acc[mi][ni] = __builtin_amdgcn_mfma_f32_16x16x32_bf16(a0, bfr[0][ni], acc[mi][ni],0,0,0);
      #pragma unroll
      for (int ni=0;ni<4;ni++)
        acc[mi][ni] = __builtin_amdgcn_mfma_f32_16x16x32_bf16(a1, bfr[1][ni], acc[mi][ni],0,0,0);
    }
    __builtin_amdgcn_s_setprio(0);
    __syncthreads();
  }
  #pragma unroll
  for (int mi=0;mi<8;mi++)
  #pragma unroll
  for (int ni=0;ni<4;ni++){
    int col = n0 + wn + ni*16 + n;
    float bsv = bias[col];
    #pragma unroll
    for (int rg=0;rg<4;rg++){
      int row = m0 + wm + mi*16 + quad*4 + rg;
      float v = acc[mi][ni][rg] + bsv;
      if (GELU) v = gelu_f(v);
      if (OUTF32) ((float*)Cp)[(size_t)row*N + col] = v;
      else ((unsigned short*)Cp)[(size_t)row*N + col] = f2bf(v);
    }
  }
}

// ---------------- MFMA banded sliding-window attention (+ global key column) ----------------
// qkv: fused [NBS, 3840] bf16 with columns [q|k|v|kg|vg]
__global__ __launch_bounds__(256, 2) void band_attn_mfma(
    const unsigned short* __restrict__ qkv, const int* __restrict__ am,
    unsigned short* __restrict__ Out){
  __shared__ unsigned short Kt[64*72];        // [key][dim], pad 72
  __shared__ unsigned short Vt[64*72];        // [dim][key], pad 72 (transposed)
  __shared__ unsigned short Pbuf[4*64*72];    // per-wave P tile [q][key], pad 72
  __shared__ float mk[64];                    // per-key additive mask (0 / -1e9)
  __shared__ unsigned short kgs[64];
  __shared__ unsigned short vgs[64];

  const int tid = threadIdx.x;
  const int bid = xcd_swz(blockIdx.x, gridDim.x);
  const int c = bid & (NCHUNK-1);
  const int h = (bid / NCHUNK) % NHEAD;
  const int b = bid / (NCHUNK*NHEAD);
  const int lane = tid & 63, w = tid >> 6;
  const int n = lane & 15, quad = lane >> 4;
  const int qbase = w * 64;
  unsigned short* Pw = Pbuf + w*64*72;

  if (tid < 8)       ((uint4*)kgs)[tid]   = ((const uint4*)(qkv + ((size_t)b*NS)*QSTR + OKG + h*DHEAD))[tid];
  else if (tid < 16) ((uint4*)vgs)[tid-8] = ((const uint4*)(qkv + ((size_t)b*NS)*QSTR + OVG + h*DHEAD))[tid-8];
  __syncthreads();

  bf16x8 aQ[4][2];
  #pragma unroll
  for (int mi=0; mi<4; mi++)
  #pragma unroll
  for (int ks=0; ks<2; ks++)
    aQ[mi][ks] = *(const bf16x8*)(qkv + ((size_t)(b*NS + c*WWIN + qbase + 16*mi + n))*QSTR
                                    + OQ + h*DHEAD + ks*32 + quad*8);

  f32x4 sacc[4] = {};
  #pragma unroll
  for (int ks=0; ks<2; ks++){
    bf16x8 bg = *(const bf16x8*)(kgs + ks*32 + quad*8);
    bf16x8 z8 = {};
    bg = (n == 0) ? bg : z8;
    #pragma unroll
    for (int mi=0; mi<4; mi++)
      sacc[mi] = __builtin_amdgcn_mfma_f32_16x16x32_bf16(aQ[mi][ks], bg, sacc[mi], 0,0,0);
  }
  float mst[4][4], lpt[4][4];
  f32x4 apv[4][4];
  float vgf[4];
  #pragma unroll
  for (int ni=0; ni<4; ni++) vgf[ni] = bf2f(vgs[16*ni + n]);
  #pragma unroll
  for (int mi=0; mi<4; mi++)
  #pragma unroll
  for (int rg=0; rg<4; rg++){
    float sg = __shfl(sacc[mi][rg], lane & 48);
    mst[mi][rg] = sg * 0.125f;
    lpt[mi][rg] = (n == 0) ? 1.0f : 0.0f;
  }
  #pragma unroll
  for (int mi=0; mi<4; mi++)
  #pragma unroll
  for (int ni=0; ni<4; ni++)
  #pragma unroll
  for (int rg=0; rg<4; rg++) apv[mi][ni][rg] = vgf[ni];

  for (int t=0; t<12; t++){
    __syncthreads();
    {
      int i = tid >> 2, d0 = (tid & 3) * 8;
      int kp = (c-1)*WWIN + t*64 + i;
      int kpc = min(max(kp, 0), NS-1);
      size_t gb = ((size_t)(b*NS + kpc))*QSTR + h*DHEAD;
      uint4 k0 = *(const uint4*)(qkv + gb + OK_ + d0);
      uint4 k1 = *(const uint4*)(qkv + gb + OK_ + d0 + 32);
      uint4 v0 = *(const uint4*)(qkv + gb + OV + d0);
      uint4 v1 = *(const uint4*)(qkv + gb + OV + d0 + 32);
      *(uint4*)(Kt + i*72 + d0) = k0;
      *(uint4*)(Kt + i*72 + d0 + 32) = k1;
      const unsigned short* s0 = (const unsigned short*)&v0;
      const unsigned short* s1 = (const unsigned short*)&v1;
      #pragma unroll
      for (int j=0;j<8;j++){
        Vt[(d0+j)*72 + i] = s0[j];
        Vt[(d0+32+j)*72 + i] = s1[j];
      }
      if ((tid & 3) == 0)
        mk[i] = (kp >= 1 && kp < NS && am[b*NS + kpc] > 0) ? 0.0f : -1e9f;
    }
    __syncthreads();

    float mkv[4];
    #pragma unroll
    for (int ni=0; ni<4; ni++) mkv[ni] = mk[16*ni + n];

    f32x4 accs[4][4] = {};
    #pragma unroll
    for (int ks=0; ks<2; ks++){
      bf16x8 bK[4];
      #pragma unroll
      for (int ni=0; ni<4; ni++)
        bK[ni] = *(const bf16x8*)(Kt + (16*ni + n)*72 + ks*32 + quad*8);
      #pragma unroll
      for (int mi=0; mi<4; mi++)
      #pragma unroll
      for (int ni=0; ni<4; ni++)
        accs[mi][ni] = __builtin_amdgcn_mfma_f32_16x16x32_bf16(aQ[mi][ks], bK[ni], accs[mi][ni], 0,0,0);
    }

    #pragma unroll
    for (int mi=0; mi<4; mi++){
      float sv[4][4];
      #pragma unroll
      for (int ni=0; ni<4; ni++)
      #pragma unroll
      for (int rg=0; rg<4; rg++){
        int kk = t*64 + 16*ni + n;
        int pr = qbase + 16*mi + quad*4 + rg;
        float s = accs[mi][ni][rg]*0.125f + mkv[ni];
        if ((unsigned)(kk - pr) > 512u) s = -1e9f;
        sv[ni][rg] = s;
      }
      #pragma unroll
      for (int rg=0; rg<4; rg++){
        float rm = fmaxf(fmaxf(sv[0][rg], sv[1][rg]), fmaxf(sv[2][rg], sv[3][rg]));
        rm = rowmax16(rm);
        float mold = mst[mi][rg];
        float mnew = fmaxf(mold, rm);
        float alpha = __expf(mold - mnew);
        mst[mi][rg] = mnew;
        float psum = 0.f;
        #pragma unroll
        for (int ni=0; ni<4; ni++){
          float pv = __expf(sv[ni][rg] - mnew);
          sv[ni][rg] = pv;
          psum += pv;
        }
        lpt[mi][rg] = lpt[mi][rg]*alpha + psum;
        #pragma unroll
        for (int ni=0; ni<4; ni++) apv[mi][ni][rg] *= alpha;
        int prow = 16*mi + quad*4 + rg;
        #pragma unroll
        for (int ni=0; ni<4; ni++)
          Pw[prow*72 + 16*ni + n] = f2bf(sv[ni][rg]);
      }
    }

    #pragma unroll
    for (int ks2=0; ks2<2; ks2++){
      bf16x8 aP[4], bV[4];
      #pragma unroll
      for (int mi=0; mi<4; mi++)
        aP[mi] = *(const bf16x8*)(Pw + (16*mi + n)*72 + ks2*32 + quad*8);
      #pragma unroll
      for (int ni=0; ni<4; ni++)
        bV[ni] = *(const bf16x8*)(Vt + (16*ni + n)*72 + ks2*32 + quad*8);
      #pragma unroll
      for (int mi=0; mi<4; mi++)
      #pragma unroll
      for (int ni=0; ni<4; ni++)
        apv[mi][ni] = __builtin_amdgcn_mfma_f32_16x16x32_bf16(aP[mi], bV[ni], apv[mi][ni], 0,0,0);
    }
  }

  #pragma unroll
  for (int mi=0; mi<4; mi++)
  #pragma unroll
  for (int rg=0; rg<4; rg++){
    float L = rowsum16(lpt[mi][rg]);
    float inv = 1.0f / L;
    int q = c*WWIN + qbase + 16*mi + quad*4 + rg;
    size_t ob = ((size_t)(b*NS + q))*HIDN + h*DHEAD;
    #pragma unroll
    for (int ni=0; ni<4; ni++)
      Out[ob + 16*ni + n] = f2bf(apv[mi][ni][rg] * inv);
  }
}

// ---------------- split-flash global (CLS) attention: partials over 128-key chunks ----
__global__ __launch_bounds__(128) void gattn_part(
    const unsigned short* __restrict__ QG0, const unsigned short* __restrict__ qkv,
    const int* __restrict__ am, float* __restrict__ part){
  __shared__ float qs[64];
  __shared__ float ps[128];
  __shared__ float red[128];
  int t = threadIdx.x;
  int cx = blockIdx.x, h = blockIdx.y, b = blockIdx.z;
  if (t < 32){
    float a, bb; unpack2(((const unsigned int*)(QG0 + (size_t)b*128*HIDN + h*DHEAD))[t], a, bb);
    qs[2*t]=a*0.125f; qs[2*t+1]=bb*0.125f;
  }
  __syncthreads();
  int kp = cx*128 + t;
  const unsigned int* kr = (const unsigned int*)(qkv + ((size_t)(b*NS+kp))*QSTR + OKG + h*DHEAD);
  float sv = 0.f;
  #pragma unroll
  for (int j=0;j<32;j++){ float a,bb; unpack2(kr[j],a,bb); sv += qs[2*j]*a + qs[2*j+1]*bb; }
  if (am[b*NS+kp] <= 0) sv = -1e9f;
  red[t] = sv; __syncthreads();
  for (int st=64; st>0; st>>=1){ if (t<st) red[t] = fmaxf(red[t], red[t+st]); __syncthreads(); }
  float M = red[0]; __syncthreads();
  float e = __expf(sv - M);
  ps[t] = e; red[t] = e; __syncthreads();
  for (int st=64; st>0; st>>=1){ if (t<st) red[t] += red[t+st]; __syncthreads(); }
  float L = red[0];
  float* po = part + ((size_t)((b*NHEAD+h)*32 + cx))*66;
  if (t==0){ po[0]=M; po[1]=L; }
  if (t < 64){
    float o = 0.f;
    #pragma unroll 4
    for (int i=0;i<128;i++)
      o += ps[i] * bf2f(qkv[((size_t)(b*NS + cx*128 + i))*QSTR + OVG + h*DHEAD + t]);
    po[2+t] = o;
  }
}

__global__ __launch_bounds__(64) void gattn_reduce(const float* __restrict__ part,
    unsigned short* __restrict__ Out){
  int bh = blockIdx.x;
  int b = bh / NHEAD, h = bh % NHEAD;
  int d = threadIdx.x;
  const float* pp = part + (size_t)bh*32*66;
  float M = -1e30f;
  for (int c2=0;c2<32;c2++) M = fmaxf(M, pp[c2*66]);
  float L = 0.f, o = 0.f;
  for (int c2=0;c2<32;c2++){
    float w = __expf(pp[c2*66] - M);
    L += pp[c2*66+1]*w;
    o += pp[c2*66+2+d]*w;
  }
  Out[((size_t)b*NS)*HIDN + h*DHEAD + d] = f2bf(o / L);
}

// ---------------- classification head on CLS token (all fp32), 4-way d-split ----
__global__ __launch_bounds__(256) void head_k(const float* __restrict__ X,
    const float* __restrict__ HW, const float* __restrict__ HB,
    float* __restrict__ Outp){
  __shared__ float red[256];
  __shared__ float xs[HIDN];
  int b = blockIdx.y;
  int base = blockIdx.x*64;
  int t = threadIdx.x;
  const float* x0 = X + (size_t)b*NS*HIDN;
  for (int i=t; i<HIDN; i+=256) xs[i] = x0[i];
  __syncthreads();
  int n = base + (t & 63);
  int dp = t >> 6;             // 0..3, 192 dims each
  float a = 0.f;
  if (n < NLABEL){
    #pragma unroll 4
    for (int d=dp*192; d<dp*192+192; ++d)
      a += xs[d] * HW[(size_t)d*NLABEL + n];
  }
  red[t] = a; __syncthreads();
  if (t < 64 && n < NLABEL)
    Outp[(size_t)b*NLABEL + n] = red[t]+red[t+64]+red[t+128]+red[t+192] + HB[n];
}

extern "C" void kernel_launch(void* const* d_in, const int* in_sizes, int n_in,
                              void* d_out, int out_size, void* d_ws, size_t ws_size,
                              hipStream_t stream){
  (void)in_sizes; (void)n_in; (void)out_size; (void)ws_size;
  const int* ids = (const int*)d_in[0];
  const int* am  = (const int*)d_in[1];
  const float* we  = (const float*)d_in[2];
  const float* pe  = (const float*)d_in[3];
  const float* elns= (const float*)d_in[4];
  const float* elnb= (const float*)d_in[5];
  const float* Wq  = (const float*)d_in[6];
  const float* bq  = (const float*)d_in[7];
  const float* Wk  = (const float*)d_in[8];
  const float* bk  = (const float*)d_in[9];
  const float* Wv  = (const float*)d_in[10];
  const float* bv  = (const float*)d_in[11];
  const float* Wqg = (const float*)d_in[12];
  const float* bqg = (const float*)d_in[13];
  const float* Wkg = (const float*)d_in[14];
  const float* bkg = (const float*)d_in[15];
  const float* Wvg = (const float*)d_in[16];
  const float* bvg = (const float*)d_in[17];
  const float* Wo  = (const float*)d_in[18];
  const float* bo  = (const float*)d_in[19];
  const float* l1s = (const float*)d_in[20];
  const float* l1b = (const float*)d_in[21];
  const float* W1  = (const float*)d_in[22];
  const float* b1  = (const float*)d_in[23];
  const float* W2  = (const float*)d_in[24];
  const float* b2  = (const float*)d_in[25];
  const float* l2s = (const float*)d_in[26];
  const float* l2b = (const float*)d_in[27];
  const float* hW  = (const float*)d_in[28];
  const float* hB  = (const float*)d_in[29];

  char* ws = (char*)d_ws;
  float* x = (float*)ws;                                    // 25,165,824 B
  float* y = (float*)(ws + 25165824);                       // 25,165,824 B
  unsigned short* xb   = (unsigned short*)(ws + 50331648);  // 12,582,912 B
  unsigned short* qkvb = (unsigned short*)(ws + 62914560);  // 8192*3840*2 = 62,914,560 B
  unsigned short* qg0b = (unsigned short*)(ws + 125829120); // 393,216 B
  float* part = (float*)(ws + 126222336);                   // 202,752 B
  unsigned short* ao   = (unsigned short*)(ws + 126425088); // 12,582,912 B
  unsigned short* hbuf = (unsigned short*)(ws + 139008000); // 50,331,648 B
  unsigned short* wt   = (unsigned short*)(ws + 189339648); // 35,389,440 B
  float* bpack = (float*)(ws + 224729088);                  // 2*3840*4 = 30,720 B

  const size_t SQ = 589824;        // 768*768
  const size_t SW = 2359296;       // 768*3072
  const size_t PERL = 7*SQ + 2*SW;

  // single fused transpose launch over all 18 weight matrices
  TrTable tt;
  int nt = 0, tacc = 0;
  for (int l=0; l<NLAYER; l++){
    unsigned short* base = wt + (size_t)l*PERL;
    const float* srcs[9] = {Wq + (size_t)l*SQ, Wk + (size_t)l*SQ, Wv + (size_t)l*SQ,
                            Wkg + (size_t)l*SQ, Wvg + (size_t)l*SQ, Wqg + (size_t)l*SQ,
                            Wo + (size_t)l*SQ, W1 + (size_t)l*SW, W2 + (size_t)l*SW};
    unsigned short* dsts[9] = {base, base+SQ, base+2*SQ, base+3*SQ, base+4*SQ,
                               base+5*SQ, base+6*SQ, base+7*SQ, base+7*SQ+SW};
    int Rs[9] = {768,768,768,768,768,768,768,768,3072};
    int Cs[9] = {768,768,768,768,768,768,768,3072,768};
    for (int k=0;k<9;k++){
      tt.src[nt]=srcs[k]; tt.dst[nt]=dsts[k]; tt.R[nt]=Rs[k]; tt.C[nt]=Cs[k];
      tt.t0[nt]=tacc; tacc += (Rs[k]/32)*(Cs[k]/32); nt++;
    }
  }
  tt.t0[18]=tacc;
  transpose_all_k<<<tacc, dim3(32,8), 0, stream>>>(tt);
  pack_bias_k<<<(NLAYER*QSTR)/256, 256, 0, stream>>>(bq, bk, bv, bkg, bvg, bpack);

  embed_k<<<(NBS*HIDN)/256, 256, 0, stream>>>(ids, we, pe, y);
  ln_k<<<NBS, 256, 0, stream>>>(y, nullptr, elns, elnb, x, xb);

  for (int l=0; l<NLAYER; l++){
    unsigned short* base = wt + (size_t)l*PERL;
    // fused q/k/v/kg/vg projection: N = 3840, 15x32 = 480 blocks (all co-resident)
    gemm256<0,0><<<dim3(15,32), 512, 0, stream>>>(xb, base, bpack + (size_t)l*QSTR,
                                                  qkvb, NBS, QSTR, 768);
    // qg for CLS rows of both batches, one launch
    gemm128qg<<<dim3(6,1,2), 256, 0, stream>>>(xb, base + 5*SQ, bqg + l*768, qg0b);
    band_attn_mfma<<<NB*NHEAD*NCHUNK, 256, 0, stream>>>(qkvb, am, ao);
    gattn_part<<<dim3(32, NHEAD, NB), 128, 0, stream>>>(qg0b, qkvb, am, part);
    gattn_reduce<<<NB*NHEAD, 64, 0, stream>>>(part, ao);
    gemm128<1,0><<<dim3(6,64), 256, 0, stream>>>(ao, base + 6*SQ, bo + l*768, y, NBS, 768, 768);
    ln_k<<<NBS, 256, 0, stream>>>(y, x, l1s + l*768, l1b + l*768, x, xb);
    // FFN1: 12x32 = 384 blocks (all co-resident at 2 blocks/CU)
    gemm256<0,1><<<dim3(12,32), 512, 0, stream>>>(xb, base + 7*SQ, b1 + l*3072, hbuf, NBS, 3072, 768);
    gemm128<1,0><<<dim3(6,64), 256, 0, stream>>>(hbuf, base + 7*SQ + SW, b2 + l*768, y, NBS, 768, 3072);
    ln_k<<<NBS, 256, 0, stream>>>(y, x, l2s + l*768, l2b + l*768, x, xb);
  }

  head_k<<<dim3((NLABEL+63)/64, NB), 256, 0, stream>>>(x, hW, hB, (float*)d_out);
}